// Round 8
// baseline (2394.075 us; speedup 1.0000x reference)
//
#include <hip/hip_runtime.h>
#include <math.h>

// ---------------------------------------------------------------------------
// LocalSlidingWindow_DisentangledAttention — Round 8: QBLK=64 attn, 256 thr,
// 52 KB LDS -> 3 independent blocks/CU (12 waves). Operand fragments (posk,
// posq, K, Vt) read DIRECT from global (L1/L2-resident, VMEM pipe) — LDS only
// for C2P scratch, p2c T tiles (aliased), and the idx LUT.
// ---------------------------------------------------------------------------

#define NHEADS 12
#define HDIM   64
#define SEQ    8192
#define HID    768
#define BSZ    128
#define WIN    384
#define PBUCK  512

typedef __attribute__((ext_vector_type(8))) short bf16x8;
typedef __attribute__((ext_vector_type(4))) float f32x4;
#define MFMA16(a, b, c) __builtin_amdgcn_mfma_f32_16x16x32_bf16((a), (b), (c), 0, 0, 0)

// attn LDS byte map (dynamic, 52224 total)
#define SM_C2P 0        // [64][392] bf16 = 50176  (phase 1-2)
#define SM_TL  0        // 4 x [32][184] bf16 = 47104 (phase 4; C2P dead)
#define SM_LUT 50176    // [511] int = 2044
#define SMEM_ATTN 52224

#define SOFT_C 0.10411790f   // log2(e)/sqrt(192)

__device__ __forceinline__ unsigned short f2bf(float f) {
  unsigned int x = __builtin_bit_cast(unsigned int, f);
  unsigned int r = (x + 0x7FFFu + ((x >> 16) & 1u)) >> 16;
  return (unsigned short)r;
}
__device__ __forceinline__ float bf2f(unsigned short u) {
  unsigned int x = ((unsigned int)u) << 16;
  return __builtin_bit_cast(float, x);
}

// idx(rel) for rel in [-383, 127]
__device__ __forceinline__ int bucket_idx(int rel) {
  if (rel >= -128) return rel + 256;
  float a = (float)(-rel);
  float t = logf(a * (1.0f / 128.0f));
  t = t / 0.6892332813f;
  t = t * 127.0f;
  int lp = (int)(ceilf(t) + 128.0f);
  int r = 256 - lp;
  return r < 0 ? 0 : r;
}

// Fragment (bf16x8) from a row-major [rows][64] bf16 global table.
// k-elements: slice*32 + g*4 + {0..3} and slice*32 + 16 + g*4 + {0..3}.
__device__ __forceinline__ bf16x8 gfrag(const unsigned short* base, int row,
                                        int slice, int g) {
  const unsigned short* p = base + (size_t)row * 64 + slice * 32 + g * 4;
  union { bf16x8 v; uint2 u2[2]; } w;
  w.u2[0] = *(const uint2*)(p);
  w.u2[1] = *(const uint2*)(p + 16);
  return w.v;
}

// K fragment with halo predication (row ks in [0,SEQ) else zeros).
__device__ __forceinline__ bf16x8 kfrag(const unsigned short* kbh, int ks,
                                        int slice, int g) {
  union { bf16x8 v; uint2 u2[2]; } w;
  if ((unsigned)ks < (unsigned)SEQ) {
    const unsigned short* p = kbh + (size_t)ks * 64 + slice * 32 + g * 4;
    w.u2[0] = *(const uint2*)(p);
    w.u2[1] = *(const uint2*)(p + 16);
  } else {
    w.u2[0] = make_uint2(0u, 0u);
    w.u2[1] = make_uint2(0u, 0u);
  }
  return w.v;
}

// V^T fragment: row d of vt [64][SEQ], cols kelem..kelem+3 and +16..+19,
// zero outside [0,SEQ) (4-elem groups never straddle the boundary).
__device__ __forceinline__ bf16x8 vfrag(const unsigned short* vtbh, int d,
                                        int kelem) {
  union { bf16x8 v; uint2 u2[2]; } w;
  const unsigned short* p = vtbh + (size_t)d * SEQ + kelem;
  w.u2[0] = ((unsigned)kelem < (unsigned)SEQ) ? *(const uint2*)(p)
                                              : make_uint2(0u, 0u);
  int k2 = kelem + 16;
  w.u2[1] = ((unsigned)k2 < (unsigned)SEQ) ? *(const uint2*)(p + 16)
                                           : make_uint2(0u, 0u);
  return w.v;
}

// ---------------------------------------------------------------------------
// Weight transpose fp32 -> bf16: Wt[z*768 + n][k] = W_z[k][n]
__global__ __launch_bounds__(256) void conv_wt(const float* __restrict__ W0,
                                               const float* __restrict__ W1,
                                               const float* __restrict__ W2,
                                               unsigned short* __restrict__ Wt) {
  __shared__ float tile[64][65];
  int bx = blockIdx.x, by = blockIdx.y, z = blockIdx.z;
  const float* W = (z == 0) ? W0 : (z == 1 ? W1 : W2);
  int t = threadIdx.x;
  int c = t & 63, r0 = (t >> 6) * 16;
#pragma unroll
  for (int rr = 0; rr < 16; ++rr)
    tile[r0 + rr][c] = W[(size_t)(by * 64 + r0 + rr) * HID + bx * 64 + c];
  __syncthreads();
#pragma unroll
  for (int rr = 0; rr < 16; ++rr) {
    int nw = r0 + rr;
    Wt[((size_t)z * HID + bx * 64 + nw) * HID + by * 64 + c] = f2bf(tile[c][nw]);
  }
}

// Positional projection (fp32 math) -> bf16 posq/posk [h][512][64]
__global__ __launch_bounds__(256) void pos_gemm(
    const float* __restrict__ relpos, const float* __restrict__ Wq,
    const float* __restrict__ Wk, const float* __restrict__ bq,
    const float* __restrict__ bk, unsigned short* __restrict__ posq,
    unsigned short* __restrict__ posk) {
  __shared__ float At[32][68];
  __shared__ float Bs[32][68];
  int m0 = blockIdx.x * 64;
  int n0 = blockIdx.y * 64;
  int w = n0 / HID;
  int nc0 = n0 % HID;
  const float* W = (w == 0) ? Wq : Wk;
  const float* bias = (w == 0) ? bq : bk;
  int t = threadIdx.x;
  int tx = t & 15, ty = t >> 4;
  float acc[4][4] = {};
  for (int k0 = 0; k0 < HID; k0 += 32) {
#pragma unroll
    for (int u = 0; u < 2; ++u) {
      int f = t * 2 + u;
      int r = f >> 3, c4 = f & 7;
      float4 av = *(const float4*)(relpos + (size_t)(m0 + r) * HID + k0 + c4 * 4);
      At[c4 * 4 + 0][r] = av.x; At[c4 * 4 + 1][r] = av.y;
      At[c4 * 4 + 2][r] = av.z; At[c4 * 4 + 3][r] = av.w;
    }
#pragma unroll
    for (int u = 0; u < 2; ++u) {
      int f = t * 2 + u;
      int kk = f >> 4, c4 = f & 15;
      float4 bv4 = *(const float4*)(W + (size_t)(k0 + kk) * HID + nc0 + c4 * 4);
      *(float4*)&Bs[kk][c4 * 4] = bv4;
    }
    __syncthreads();
#pragma unroll
    for (int kk = 0; kk < 32; ++kk) {
      float4 a4 = *(const float4*)&At[kk][ty * 4];
      float4 b4 = *(const float4*)&Bs[kk][tx * 4];
      float av[4] = {a4.x, a4.y, a4.z, a4.w};
      float bvv[4] = {b4.x, b4.y, b4.z, b4.w};
#pragma unroll
      for (int i = 0; i < 4; ++i)
#pragma unroll
        for (int jj = 0; jj < 4; ++jj) acc[i][jj] += av[i] * bvv[jj];
    }
    __syncthreads();
  }
  int h = nc0 >> 6;
  unsigned short* dst = (w == 0) ? posq : posk;
#pragma unroll
  for (int i = 0; i < 4; ++i) {
    int p = m0 + ty * 4 + i;
    ushort4 o;
    o.x = f2bf(acc[i][0] + bias[nc0 + tx * 4 + 0]);
    o.y = f2bf(acc[i][1] + bias[nc0 + tx * 4 + 1]);
    o.z = f2bf(acc[i][2] + bias[nc0 + tx * 4 + 2]);
    o.w = f2bf(acc[i][3] + bias[nc0 + tx * 4 + 3]);
    *(ushort4*)(dst + ((size_t)h * PBUCK + p) * HDIM + tx * 4) = o;
  }
}

// ---------------------------------------------------------------------------
// QKV projection, bf16 MFMA. Tile 128x128, BK=64, 256 thr = 4 waves (2x2).
__global__ __launch_bounds__(256) void qkv_mfma(
    const float* __restrict__ hidden, const unsigned short* __restrict__ Wt,
    const float* __restrict__ bq, const float* __restrict__ bk,
    const float* __restrict__ bv, unsigned short* __restrict__ qws,
    unsigned short* __restrict__ kws, unsigned short* __restrict__ vt) {
  __shared__ unsigned short As[8192];
  __shared__ unsigned short Bs[8192];
  const int t = threadIdx.x;
  const int lane = t & 63;
  const int l15 = lane & 15, g = lane >> 4;
  const int wave = t >> 6;
  const int wy = wave >> 1, wx = wave & 1;
  const int n0 = blockIdx.x * 128;
  const int m0 = blockIdx.y * 128;

  f32x4 acc[4][4];
#pragma unroll
  for (int i = 0; i < 4; ++i)
#pragma unroll
    for (int j = 0; j < 4; ++j) acc[i][j] = (f32x4){0.f, 0.f, 0.f, 0.f};

  for (int k0 = 0; k0 < HID; k0 += 64) {
#pragma unroll
    for (int i = 0; i < 4; ++i) {
      int c = t + i * 256;
      int row = c >> 3, cx = c & 7;
      const float4* src =
          (const float4*)(hidden + (size_t)(m0 + row) * HID + k0 + cx * 8);
      float4 a = src[0], b = src[1];
      union { bf16x8 v; unsigned short u[8]; } w;
      w.u[0] = f2bf(a.x); w.u[1] = f2bf(a.y); w.u[2] = f2bf(a.z); w.u[3] = f2bf(a.w);
      w.u[4] = f2bf(b.x); w.u[5] = f2bf(b.y); w.u[6] = f2bf(b.z); w.u[7] = f2bf(b.w);
      *(bf16x8*)((char*)As + row * 128 + ((cx * 16) ^ ((row & 7) << 4))) = w.v;
    }
#pragma unroll
    for (int i = 0; i < 4; ++i) {
      int c = t + i * 256;
      int row = c >> 3, cx = c & 7;
      uint4 v = *(const uint4*)(Wt + (size_t)(n0 + row) * HID + k0 + cx * 8);
      *(uint4*)((char*)Bs + row * 128 + ((cx * 16) ^ ((row & 7) << 4))) = v;
    }
    __syncthreads();
    bf16x8 af[4][2], bf[4][2];
#pragma unroll
    for (int mt = 0; mt < 4; ++mt) {
      int row = wy * 64 + mt * 16 + l15;
      const char* p = (const char*)As + row * 128;
      int swz = (row & 7) << 4;
#pragma unroll
      for (int s = 0; s < 2; ++s)
        af[mt][s] = *(const bf16x8*)(p + ((s * 64 + g * 16) ^ swz));
    }
#pragma unroll
    for (int nt = 0; nt < 4; ++nt) {
      int row = wx * 64 + nt * 16 + l15;
      const char* p = (const char*)Bs + row * 128;
      int swz = (row & 7) << 4;
#pragma unroll
      for (int s = 0; s < 2; ++s)
        bf[nt][s] = *(const bf16x8*)(p + ((s * 64 + g * 16) ^ swz));
    }
#pragma unroll
    for (int mt = 0; mt < 4; ++mt)
#pragma unroll
      for (int nt = 0; nt < 4; ++nt) {
        acc[mt][nt] = MFMA16(af[mt][0], bf[nt][0], acc[mt][nt]);
        acc[mt][nt] = MFMA16(af[mt][1], bf[nt][1], acc[mt][nt]);
      }
    __syncthreads();
  }

  const int w = n0 / HID;
  const float* bias = (w == 0) ? bq : (w == 1 ? bk : bv);
#pragma unroll
  for (int nt = 0; nt < 4; ++nt) {
    int gn = n0 + wx * 64 + nt * 16 + l15;
    int nc = gn - w * HID;
    int h = nc >> 6, d = nc & 63;
    float bval = bias[nc];
#pragma unroll
    for (int mt = 0; mt < 4; ++mt) {
      f32x4 a = acc[mt][nt];
#pragma unroll
      for (int r = 0; r < 4; ++r) {
        int m = m0 + wy * 64 + mt * 16 + 4 * g + r;
        int bl = m >> 13, s = m & 8191;
        size_t bh = (size_t)bl * NHEADS + h;
        unsigned short val = f2bf(a[r] + bval);
        if (w == 0)
          qws[(bh * SEQ + s) * HDIM + d] = val;
        else if (w == 1)
          kws[(bh * SEQ + s) * HDIM + d] = val;
        else
          vt[bh * ((size_t)HDIM * SEQ) + (size_t)d * SEQ + s] = val;
      }
    }
  }
}

// ---------------------------------------------------------------------------
// MFMA attention, QBLK=64: block = (b,h,n,qh), 4 waves. Wave owns 16 q rows.
// acc[24] f32x4: S[k=16t+4g+r][q(local)=qs+l15]. Fragments direct from global.
__global__ __launch_bounds__(256, 3) void attn_kernel(
    const unsigned short* __restrict__ qws, const unsigned short* __restrict__ kws,
    const unsigned short* __restrict__ vt, const unsigned short* __restrict__ posq,
    const unsigned short* __restrict__ posk, unsigned short* __restrict__ ctx) {
  extern __shared__ char smem[];
  int* iLUT = (int*)(smem + SM_LUT);

  const int tid = threadIdx.x;
  const int wave = tid >> 6;
  const int lane = tid & 63;
  const int l15 = lane & 15;
  const int g = lane >> 4;
  const int qs = wave << 4;          // local q-strip base (0..48)
  const int ql = qs + l15;           // local q row (0..63)

  const int bid = blockIdx.x;
  const int qh = bid & 1;
  const int n = (bid >> 1) & 63;
  const int bh = bid >> 7;
  const int h = bh % NHEADS;
  const int b = bh / NHEADS;

  const int q128 = qh * 64 + ql;     // q position within the n-block (0..127)
  const int kbase = n * BSZ - BSZ;   // window start (global row)

  const unsigned short* kbh = kws + (size_t)bh * SEQ * HDIM;
  const unsigned short* vtbh = vt + (size_t)bh * ((size_t)HDIM * SEQ);
  const unsigned short* pqh = posq + (size_t)h * PBUCK * HDIM;
  const unsigned short* pkh = posk + (size_t)h * PBUCK * HDIM;

  // ---- phase 0: LUT; Q fragments direct from global
  for (int i = tid; i < 511; i += 256) iLUT[i] = bucket_idx(i - 383);

  bf16x8 qf0, qf1;
  {
    const unsigned short* qrow =
        qws + ((size_t)bh * SEQ + n * BSZ + qh * 64 + ql) * HDIM;
    qf0 = gfrag(qrow, 0, 0, g);
    qf1 = gfrag(qrow, 0, 1, g);
  }

  // ---- phase 1: C2P[ql][p] = Q . posk^T (24 p-tiles; B-frags from global)
  unsigned short* C2P = (unsigned short*)(smem + SM_C2P);
  __builtin_amdgcn_s_setprio(1);
#pragma unroll
  for (int ntl = 0; ntl < 24; ++ntl) {
    int prow = 16 * ntl + l15;
    bf16x8 b0 = gfrag(pkh, prow, 0, g);
    bf16x8 b1 = gfrag(pkh, prow, 1, g);
    f32x4 c = {0.f, 0.f, 0.f, 0.f};
    c = MFMA16(qf0, b0, c);
    c = MFMA16(qf1, b1, c);
#pragma unroll
    for (int r = 0; r < 4; ++r)
      C2P[(qs + 4 * g + r) * 392 + prow] = f2bf(c[r]);
  }
  __builtin_amdgcn_s_setprio(0);
  __syncthreads();  // B1: C2P + LUT ready

  // ---- phase 2: gather c2p into acc
  f32x4 acc[24];
  {
    const unsigned short* c2pRow = C2P + ql * 392;
#pragma unroll
    for (int t = 0; t < 24; ++t) {
#pragma unroll
      for (int r = 0; r < 4; ++r) {
        int k = 16 * t + 4 * g + r;
        int rel = q128 - k;
        int idxv = (rel >= -128) ? (rel + 256) : iLUT[rel + 383];
        acc[t][r] = bf2f(c2pRow[idxv]);
      }
    }
  }
  __syncthreads();  // B2: C2P dead (Tl aliases it)

  // ---- phase 4: p2c, 3 rounds x 4 subtiles (32 k each); frags from global
  unsigned short* Tl = (unsigned short*)(smem + SM_TL);
#pragma unroll
  for (int rr = 0; rr < 3; ++rr) {
    const int s0 = 4 * rr;
    const int lo0 = iLUT[352 - 32 * (s0 + 0)];
    const int lo1 = iLUT[352 - 32 * (s0 + 1)];
    const int lo2 = iLUT[352 - 32 * (s0 + 2)];
    const int lo3 = iLUT[352 - 32 * (s0 + 3)];
    const int n0_ = ((iLUT[510 - 32 * (s0 + 0)] - lo0 + 1) + 15) >> 4;
    const int n1_ = ((iLUT[510 - 32 * (s0 + 1)] - lo1 + 1) + 15) >> 4;
    const int n2_ = ((iLUT[510 - 32 * (s0 + 2)] - lo2 + 1) + 15) >> 4;
    const int n3_ = ((iLUT[510 - 32 * (s0 + 3)] - lo3 + 1) + 15) >> 4;
    const int e0 = 2 * n0_, e1 = e0 + 2 * n1_, e2 = e1 + 2 * n2_,
              e3 = e2 + 2 * n3_;
    for (int j = wave; j < e3; j += 4) {
      int u, jj, lo;
      if (j < e0)      { u = 0; jj = j;      lo = lo0; }
      else if (j < e1) { u = 1; jj = j - e0; lo = lo1; }
      else if (j < e2) { u = 2; jj = j - e1; lo = lo2; }
      else             { u = 3; jj = j - e2; lo = lo3; }
      int mt = jj & 1, ntl = jj >> 1;
      int s = s0 + u;
      int ks = kbase + 32 * s + 16 * mt + l15;
      bf16x8 a0 = kfrag(kbh, ks, 0, g);
      bf16x8 a1 = kfrag(kbh, ks, 1, g);
      int prow = lo + 16 * ntl + l15;
      prow = prow > 383 ? 383 : prow;
      bf16x8 b0 = gfrag(pqh, prow, 0, g);
      bf16x8 b1 = gfrag(pqh, prow, 1, g);
      f32x4 c = {0.f, 0.f, 0.f, 0.f};
      c = MFMA16(a0, b0, c);
      c = MFMA16(a1, b1, c);
#pragma unroll
      for (int r = 0; r < 4; ++r)
        Tl[u * 5888 + (16 * mt + 4 * g + r) * 184 + 16 * ntl + l15] =
            f2bf(c[r]);
    }
    __syncthreads();  // Tl ready
#pragma unroll
    for (int u = 0; u < 4; ++u) {
      const int s = s0 + u;
      const int lo = (u == 0) ? lo0 : (u == 1) ? lo1 : (u == 2) ? lo2 : lo3;
#pragma unroll
      for (int tt = 0; tt < 2; ++tt) {
#pragma unroll
        for (int r = 0; r < 4; ++r) {
          int k = 32 * s + 16 * tt + 4 * g + r;
          int rel = q128 - k;
          int idxv = (rel >= -128) ? (rel + 256) : iLUT[rel + 383];
          acc[8 * rr + 2 * u + tt][r] +=
              bf2f(Tl[u * 5888 + (16 * tt + 4 * g + r) * 184 + idxv - lo]);
        }
      }
    }
    __syncthreads();  // Tl reusable
  }

  // ---- phase 5: QK^T accumulate (A = K rows from global, B = Q^T)
  __builtin_amdgcn_s_setprio(1);
#pragma unroll
  for (int t = 0; t < 24; ++t) {
    int ks = kbase + 16 * t + l15;
    bf16x8 a0 = kfrag(kbh, ks, 0, g);
    bf16x8 a1 = kfrag(kbh, ks, 1, g);
    acc[t] = MFMA16(a0, qf0, acc[t]);
    acc[t] = MFMA16(a1, qf1, acc[t]);
  }
  __builtin_amdgcn_s_setprio(0);

  // ---- phase 7: softmax (full 384 per lane's q row)
  float m = -1e30f;
#pragma unroll
  for (int t = 0; t < 24; ++t)
#pragma unroll
    for (int r = 0; r < 4; ++r) m = fmaxf(m, acc[t][r]);
  m = fmaxf(m, __shfl_xor(m, 16));
  m = fmaxf(m, __shfl_xor(m, 32));
  float sum = 0.f;
#pragma unroll
  for (int t = 0; t < 24; ++t)
#pragma unroll
    for (int r = 0; r < 4; ++r) {
      float p = exp2f((acc[t][r] - m) * SOFT_C);
      acc[t][r] = p;
      sum += p;
    }
  sum += __shfl_xor(sum, 16);
  sum += __shfl_xor(sum, 32);
  float inv = 1.0f / sum;

  bf16x8 pa[12];
#pragma unroll
  for (int kt = 0; kt < 12; ++kt) {
    union { bf16x8 v; unsigned short u[8]; } w;
#pragma unroll
    for (int j = 0; j < 4; ++j) w.u[j] = f2bf(acc[2 * kt][j] * inv);
#pragma unroll
    for (int j = 0; j < 4; ++j) w.u[4 + j] = f2bf(acc[2 * kt + 1][j] * inv);
    pa[kt] = w.v;
  }

  // ---- phase 8: PV (B = V^T fragments direct from global), write ctx
  unsigned short* ctxg =
      ctx + ((size_t)b * SEQ + n * BSZ + qh * 64) * HID + h * HDIM;
  __builtin_amdgcn_s_setprio(1);
#pragma unroll
  for (int nt = 0; nt < 4; ++nt) {
    f32x4 o = {0.f, 0.f, 0.f, 0.f};
#pragma unroll
    for (int kt = 0; kt < 12; ++kt) {
      bf16x8 bv = vfrag(vtbh, 16 * nt + l15, kbase + kt * 32 + g * 4);
      o = MFMA16(pa[kt], bv, o);
    }
#pragma unroll
    for (int r = 0; r < 4; ++r) {
      size_t off = (size_t)(qs + 4 * g + r) * HID + 16 * nt + l15;
      ctxg[off] = f2bf(o[r]);
    }
  }
  __builtin_amdgcn_s_setprio(0);
}

// ---------------------------------------------------------------------------
// Out projection bf16 MFMA + bias + residual -> fp32 out.
__global__ __launch_bounds__(256) void out_mfma(
    const unsigned short* __restrict__ ctx, const unsigned short* __restrict__ WoT,
    const float* __restrict__ bo, const float* __restrict__ hidden,
    float* __restrict__ out) {
  __shared__ unsigned short As[8192];
  __shared__ unsigned short Bs[8192];
  const int t = threadIdx.x;
  const int lane = t & 63;
  const int l15 = lane & 15, g = lane >> 4;
  const int wave = t >> 6;
  const int wy = wave >> 1, wx = wave & 1;
  const int n0 = blockIdx.x * 128;
  const int m0 = blockIdx.y * 128;

  f32x4 acc[4][4];
#pragma unroll
  for (int i = 0; i < 4; ++i)
#pragma unroll
    for (int j = 0; j < 4; ++j) acc[i][j] = (f32x4){0.f, 0.f, 0.f, 0.f};

  for (int k0 = 0; k0 < HID; k0 += 64) {
#pragma unroll
    for (int i = 0; i < 4; ++i) {
      int c = t + i * 256;
      int row = c >> 3, cx = c & 7;
      uint4 v = *(const uint4*)(ctx + (size_t)(m0 + row) * HID + k0 + cx * 8);
      *(uint4*)((char*)As + row * 128 + ((cx * 16) ^ ((row & 7) << 4))) = v;
    }
#pragma unroll
    for (int i = 0; i < 4; ++i) {
      int c = t + i * 256;
      int row = c >> 3, cx = c & 7;
      uint4 v = *(const uint4*)(WoT + (size_t)(n0 + row) * HID + k0 + cx * 8);
      *(uint4*)((char*)Bs + row * 128 + ((cx * 16) ^ ((row & 7) << 4))) = v;
    }
    __syncthreads();
    bf16x8 af[4][2], bf[4][2];
#pragma unroll
    for (int mt = 0; mt < 4; ++mt) {
      int row = wy * 64 + mt * 16 + l15;
      const char* p = (const char*)As + row * 128;
      int swz = (row & 7) << 4;
#pragma unroll
      for (int s = 0; s < 2; ++s)
        af[mt][s] = *(const bf16x8*)(p + ((s * 64 + g * 16) ^ swz));
    }
#pragma unroll
    for (int nt = 0; nt < 4; ++nt) {
      int row = wx * 64 + nt * 16 + l15;
      const char* p = (const char*)Bs + row * 128;
      int swz = (row & 7) << 4;
#pragma unroll
      for (int s = 0; s < 2; ++s)
        bf[nt][s] = *(const bf16x8*)(p + ((s * 64 + g * 16) ^ swz));
    }
#pragma unroll
    for (int mt = 0; mt < 4; ++mt)
#pragma unroll
      for (int nt = 0; nt < 4; ++nt) {
        acc[mt][nt] = MFMA16(af[mt][0], bf[nt][0], acc[mt][nt]);
        acc[mt][nt] = MFMA16(af[mt][1], bf[nt][1], acc[mt][nt]);
      }
    __syncthreads();
  }

#pragma unroll
  for (int nt = 0; nt < 4; ++nt) {
    int gn = n0 + wx * 64 + nt * 16 + l15;
    float bval = bo[gn];
#pragma unroll
    for (int mt = 0; mt < 4; ++mt) {
      f32x4 a = acc[mt][nt];
#pragma unroll
      for (int r = 0; r < 4; ++r) {
        int m = m0 + wy * 64 + mt * 16 + 4 * g + r;
        size_t off = (size_t)m * HID + gn;
        out[off] = a[r] + bval + hidden[off];
      }
    }
  }
}

// In-place LayerNorm over rows of 768.
__global__ __launch_bounds__(256) void ln_kernel(float* __restrict__ x,
                                                 const float* __restrict__ sc,
                                                 const float* __restrict__ bi) {
  __shared__ float red[8];
  int row = blockIdx.x;
  int t = threadIdx.x;
  float* xr = x + (size_t)row * HID;
  float e0 = xr[t], e1 = xr[t + 256], e2 = xr[t + 512];
  float ssum = e0 + e1 + e2;
#pragma unroll
  for (int o = 1; o < 64; o <<= 1) ssum += __shfl_xor(ssum, o);
  int w = t >> 6;
  if ((t & 63) == 0) red[w] = ssum;
  __syncthreads();
  float mu = (red[0] + red[1] + red[2] + red[3]) * (1.0f / 768.0f);
  float d0 = e0 - mu, d1 = e1 - mu, d2 = e2 - mu;
  float sq = d0 * d0 + d1 * d1 + d2 * d2;
#pragma unroll
  for (int o = 1; o < 64; o <<= 1) sq += __shfl_xor(sq, o);
  __syncthreads();
  if ((t & 63) == 0) red[4 + w] = sq;
  __syncthreads();
  float var = (red[4] + red[5] + red[6] + red[7]) * (1.0f / 768.0f);
  float rstd = 1.0f / sqrtf(var + 1e-7f);
  xr[t] = d0 * rstd * sc[t] + bi[t];
  xr[t + 256] = d1 * rstd * sc[t + 256] + bi[t + 256];
  xr[t + 512] = d2 * rstd * sc[t + 512] + bi[t + 512];
}

extern "C" void kernel_launch(void* const* d_in, const int* in_sizes, int n_in,
                              void* d_out, int out_size, void* d_ws,
                              size_t ws_size, hipStream_t stream) {
  (void)in_sizes; (void)n_in; (void)out_size; (void)ws_size;
  const float* hidden = (const float*)d_in[0];
  const float* relpos = (const float*)d_in[1];
  const float* Wq = (const float*)d_in[2];
  const float* bq = (const float*)d_in[3];
  const float* Wk = (const float*)d_in[4];
  const float* bk = (const float*)d_in[5];
  const float* Wv = (const float*)d_in[6];
  const float* bv = (const float*)d_in[7];
  const float* Wo = (const float*)d_in[8];
  const float* bo = (const float*)d_in[9];
  const float* lns = (const float*)d_in[10];
  const float* lnb = (const float*)d_in[11];
  float* out = (float*)d_out;

  // Workspace (ushort units): q | k | vt | ctx | posq | posk | WqkvT(=WoT)
  unsigned short* ws = (unsigned short*)d_ws;
  const size_t QE = (size_t)48 * SEQ * HDIM;  // 25,165,824
  unsigned short* qws = ws;
  unsigned short* kws = qws + QE;
  unsigned short* vt = kws + QE;
  unsigned short* ctx = vt + QE;
  unsigned short* posq = ctx + QE;
  unsigned short* posk = posq + (size_t)NHEADS * PBUCK * HDIM;
  unsigned short* WqkvT = posk + (size_t)NHEADS * PBUCK * HDIM;
  unsigned short* WoT = WqkvT;  // alias: WqkvT dead before conv of Wo

  static bool attrib_set = false;
  if (!attrib_set) {
    hipFuncSetAttribute((const void*)attn_kernel,
                        hipFuncAttributeMaxDynamicSharedMemorySize, SMEM_ATTN);
    attrib_set = true;
  }

  conv_wt<<<dim3(12, 12, 3), 256, 0, stream>>>(Wq, Wk, Wv, WqkvT);
  pos_gemm<<<dim3(8, 24), 256, 0, stream>>>(relpos, Wq, Wk, bq, bk, posq, posk);
  qkv_mfma<<<dim3(18, 256), 256, 0, stream>>>(hidden, WqkvT, bq, bk, bv, qws,
                                              kws, vt);
  conv_wt<<<dim3(12, 12, 1), 256, 0, stream>>>(Wo, Wo, Wo, WoT);
  attn_kernel<<<6144, 256, SMEM_ATTN, stream>>>(qws, kws, vt, posq, posk, ctx);
  out_mfma<<<dim3(6, 256), 256, 0, stream>>>(ctx, WoT, bo, hidden, out);
  ln_kernel<<<32768, 256, 0, stream>>>(out, lns, lnb);
}

// Round 9
// 816.100 us; speedup vs baseline: 2.9336x; 2.9336x over previous
//
#include <hip/hip_runtime.h>
#include <math.h>

// ---------------------------------------------------------------------------
// LocalSlidingWindow_DisentangledAttention — Round 9:
//  - attn: exact R4 kernel (proven 434us)
//  - qkv_mfma: v written coalesced [s][d] into ctx region (vws); NEW
//    vt_transpose kernel makes vt [d][s] (fixes the 2B x 16KB-stride scatter)
//  - out_ln: fused out-projection + bias + residual + LayerNorm
// ---------------------------------------------------------------------------

#define NHEADS 12
#define HDIM   64
#define SEQ    8192
#define HID    768
#define BSZ    128
#define WIN    384
#define PBUCK  512

typedef __attribute__((ext_vector_type(8))) short bf16x8;
typedef __attribute__((ext_vector_type(4))) float f32x4;
#define MFMA16(a, b, c) __builtin_amdgcn_mfma_f32_16x16x32_bf16((a), (b), (c), 0, 0, 0)

// attn LDS byte map (dynamic, 155136 total) — R4 layout
#define C2P_OFF 0        // [128][392] bf16 = 100352   (phase 1-2)
#define K_OFF   0        // [384][64]  bf16 = 49152    (phase 3+)
#define PQ_OFF  49152    // [384][64]  bf16 = 49152    (phase 3-4)
#define VT_OFF  49152    // [64][384]  bf16 = 49152    (PV phase)
#define T_OFF   100352   // [32][184]  bf16 = 11776
#define Q_OFF   112128   // [128][64]  bf16 = 16384
#define PKH_OFF 128512   // [192][64]  bf16 = 24576
#define LUT_OFF 153088   // [511] int  = 2044
#define SMEM_ATTN 155136

// out_ln LDS byte map (dynamic, 71168)
#define OL_AU 0          // [64][40] bf16 = 5120
#define OL_BU 5120       // [768][40] bf16 = 61440
#define OL_R1 66560      // [64][8] f32 = 2048
#define OL_R2 68608      // [64][8] f32 = 2048
#define OL_MU 70656      // [64] f32
#define OL_RS 70912      // [64] f32
#define SMEM_OL 71168

__device__ __forceinline__ unsigned short f2bf(float f) {
  unsigned int x = __builtin_bit_cast(unsigned int, f);
  unsigned int r = (x + 0x7FFFu + ((x >> 16) & 1u)) >> 16;
  return (unsigned short)r;
}
__device__ __forceinline__ float bf2f(unsigned short u) {
  unsigned int x = ((unsigned int)u) << 16;
  return __builtin_bit_cast(float, x);
}

// idx(rel) for rel in [-383, 127]
__device__ __forceinline__ int bucket_idx(int rel) {
  if (rel >= -128) return rel + 256;
  float a = (float)(-rel);
  float t = logf(a * (1.0f / 128.0f));
  t = t / 0.6892332813f;
  t = t * 127.0f;
  int lp = (int)(ceilf(t) + 128.0f);
  int r = 256 - lp;
  return r < 0 ? 0 : r;
}

// Fragment load from swizzled row-major bf16 LDS tile.
__device__ __forceinline__ bf16x8 ldfrag(const char* sm, int byteBase, int row,
                                         int rowBytes, int slice, int g) {
  const int swz = (row & 7) << 4;
  const char* p = sm + byteBase + row * rowBytes;
  union { bf16x8 v; uint2 u2[2]; } w;
  w.u2[0] = *(const uint2*)(p + (((slice << 6) + (g << 3)) ^ swz));
  w.u2[1] = *(const uint2*)(p + (((slice << 6) + 32 + (g << 3)) ^ swz));
  return w.v;
}

// Fragment from padded (40-ushort rows, no swizzle) LDS tile for out_ln.
__device__ __forceinline__ bf16x8 olfrag(const unsigned short* base, int row,
                                         int g) {
  const unsigned short* p = base + row * 40 + 4 * g;
  union { bf16x8 v; uint2 u2[2]; } w;
  w.u2[0] = *(const uint2*)(p);
  w.u2[1] = *(const uint2*)(p + 16);
  return w.v;
}

// ---------------------------------------------------------------------------
// Weight transpose fp32 -> bf16: Wt[z*768 + n][k] = W_z[k][n]
__global__ __launch_bounds__(256) void conv_wt(const float* __restrict__ W0,
                                               const float* __restrict__ W1,
                                               const float* __restrict__ W2,
                                               unsigned short* __restrict__ Wt) {
  __shared__ float tile[64][65];
  int bx = blockIdx.x, by = blockIdx.y, z = blockIdx.z;
  const float* W = (z == 0) ? W0 : (z == 1 ? W1 : W2);
  int t = threadIdx.x;
  int c = t & 63, r0 = (t >> 6) * 16;
#pragma unroll
  for (int rr = 0; rr < 16; ++rr)
    tile[r0 + rr][c] = W[(size_t)(by * 64 + r0 + rr) * HID + bx * 64 + c];
  __syncthreads();
#pragma unroll
  for (int rr = 0; rr < 16; ++rr) {
    int nw = r0 + rr;
    Wt[((size_t)z * HID + bx * 64 + nw) * HID + by * 64 + c] = f2bf(tile[c][nw]);
  }
}

// Positional projection (fp32 math) -> bf16 posq/posk [h][512][64]
__global__ __launch_bounds__(256) void pos_gemm(
    const float* __restrict__ relpos, const float* __restrict__ Wq,
    const float* __restrict__ Wk, const float* __restrict__ bq,
    const float* __restrict__ bk, unsigned short* __restrict__ posq,
    unsigned short* __restrict__ posk) {
  __shared__ float At[32][68];
  __shared__ float Bs[32][68];
  int m0 = blockIdx.x * 64;
  int n0 = blockIdx.y * 64;
  int w = n0 / HID;
  int nc0 = n0 % HID;
  const float* W = (w == 0) ? Wq : Wk;
  const float* bias = (w == 0) ? bq : bk;
  int t = threadIdx.x;
  int tx = t & 15, ty = t >> 4;
  float acc[4][4] = {};
  for (int k0 = 0; k0 < HID; k0 += 32) {
#pragma unroll
    for (int u = 0; u < 2; ++u) {
      int f = t * 2 + u;
      int r = f >> 3, c4 = f & 7;
      float4 av = *(const float4*)(relpos + (size_t)(m0 + r) * HID + k0 + c4 * 4);
      At[c4 * 4 + 0][r] = av.x; At[c4 * 4 + 1][r] = av.y;
      At[c4 * 4 + 2][r] = av.z; At[c4 * 4 + 3][r] = av.w;
    }
#pragma unroll
    for (int u = 0; u < 2; ++u) {
      int f = t * 2 + u;
      int kk = f >> 4, c4 = f & 15;
      float4 bv4 = *(const float4*)(W + (size_t)(k0 + kk) * HID + nc0 + c4 * 4);
      *(float4*)&Bs[kk][c4 * 4] = bv4;
    }
    __syncthreads();
#pragma unroll
    for (int kk = 0; kk < 32; ++kk) {
      float4 a4 = *(const float4*)&At[kk][ty * 4];
      float4 b4 = *(const float4*)&Bs[kk][tx * 4];
      float av[4] = {a4.x, a4.y, a4.z, a4.w};
      float bvv[4] = {b4.x, b4.y, b4.z, b4.w};
#pragma unroll
      for (int i = 0; i < 4; ++i)
#pragma unroll
        for (int jj = 0; jj < 4; ++jj) acc[i][jj] += av[i] * bvv[jj];
    }
    __syncthreads();
  }
  int h = nc0 >> 6;
  unsigned short* dst = (w == 0) ? posq : posk;
#pragma unroll
  for (int i = 0; i < 4; ++i) {
    int p = m0 + ty * 4 + i;
    ushort4 o;
    o.x = f2bf(acc[i][0] + bias[nc0 + tx * 4 + 0]);
    o.y = f2bf(acc[i][1] + bias[nc0 + tx * 4 + 1]);
    o.z = f2bf(acc[i][2] + bias[nc0 + tx * 4 + 2]);
    o.w = f2bf(acc[i][3] + bias[nc0 + tx * 4 + 3]);
    *(ushort4*)(dst + ((size_t)h * PBUCK + p) * HDIM + tx * 4) = o;
  }
}

// ---------------------------------------------------------------------------
// QKV projection, bf16 MFMA. Tile 128x128, BK=64, 256 thr = 4 waves (2x2).
// ALL outputs (q, k, v) now written coalesced [bh][s][d]; v goes to vws.
__global__ __launch_bounds__(256) void qkv_mfma(
    const float* __restrict__ hidden, const unsigned short* __restrict__ Wt,
    const float* __restrict__ bq, const float* __restrict__ bk,
    const float* __restrict__ bv, unsigned short* __restrict__ qws,
    unsigned short* __restrict__ kws, unsigned short* __restrict__ vws) {
  __shared__ unsigned short As[8192];
  __shared__ unsigned short Bs[8192];
  const int t = threadIdx.x;
  const int lane = t & 63;
  const int l15 = lane & 15, g = lane >> 4;
  const int wave = t >> 6;
  const int wy = wave >> 1, wx = wave & 1;
  const int n0 = blockIdx.x * 128;
  const int m0 = blockIdx.y * 128;

  f32x4 acc[4][4];
#pragma unroll
  for (int i = 0; i < 4; ++i)
#pragma unroll
    for (int j = 0; j < 4; ++j) acc[i][j] = (f32x4){0.f, 0.f, 0.f, 0.f};

  for (int k0 = 0; k0 < HID; k0 += 64) {
#pragma unroll
    for (int i = 0; i < 4; ++i) {
      int c = t + i * 256;
      int row = c >> 3, cx = c & 7;
      const float4* src =
          (const float4*)(hidden + (size_t)(m0 + row) * HID + k0 + cx * 8);
      float4 a = src[0], b = src[1];
      union { bf16x8 v; unsigned short u[8]; } w;
      w.u[0] = f2bf(a.x); w.u[1] = f2bf(a.y); w.u[2] = f2bf(a.z); w.u[3] = f2bf(a.w);
      w.u[4] = f2bf(b.x); w.u[5] = f2bf(b.y); w.u[6] = f2bf(b.z); w.u[7] = f2bf(b.w);
      *(bf16x8*)((char*)As + row * 128 + ((cx * 16) ^ ((row & 7) << 4))) = w.v;
    }
#pragma unroll
    for (int i = 0; i < 4; ++i) {
      int c = t + i * 256;
      int row = c >> 3, cx = c & 7;
      uint4 v = *(const uint4*)(Wt + (size_t)(n0 + row) * HID + k0 + cx * 8);
      *(uint4*)((char*)Bs + row * 128 + ((cx * 16) ^ ((row & 7) << 4))) = v;
    }
    __syncthreads();
    bf16x8 af[4][2], bf[4][2];
#pragma unroll
    for (int mt = 0; mt < 4; ++mt) {
      int row = wy * 64 + mt * 16 + l15;
      const char* p = (const char*)As + row * 128;
      int swz = (row & 7) << 4;
#pragma unroll
      for (int s = 0; s < 2; ++s)
        af[mt][s] = *(const bf16x8*)(p + ((s * 64 + g * 16) ^ swz));
    }
#pragma unroll
    for (int nt = 0; nt < 4; ++nt) {
      int row = wx * 64 + nt * 16 + l15;
      const char* p = (const char*)Bs + row * 128;
      int swz = (row & 7) << 4;
#pragma unroll
      for (int s = 0; s < 2; ++s)
        bf[nt][s] = *(const bf16x8*)(p + ((s * 64 + g * 16) ^ swz));
    }
#pragma unroll
    for (int mt = 0; mt < 4; ++mt)
#pragma unroll
      for (int nt = 0; nt < 4; ++nt) {
        acc[mt][nt] = MFMA16(af[mt][0], bf[nt][0], acc[mt][nt]);
        acc[mt][nt] = MFMA16(af[mt][1], bf[nt][1], acc[mt][nt]);
      }
    __syncthreads();
  }

  const int w = n0 / HID;  // 0:q 1:k 2:v
  const float* bias = (w == 0) ? bq : (w == 1 ? bk : bv);
  unsigned short* dst = (w == 0) ? qws : (w == 1 ? kws : vws);
#pragma unroll
  for (int nt = 0; nt < 4; ++nt) {
    int gn = n0 + wx * 64 + nt * 16 + l15;
    int nc = gn - w * HID;
    int h = nc >> 6, d = nc & 63;
    float bval = bias[nc];
#pragma unroll
    for (int mt = 0; mt < 4; ++mt) {
      f32x4 a = acc[mt][nt];
#pragma unroll
      for (int r = 0; r < 4; ++r) {
        int m = m0 + wy * 64 + mt * 16 + 4 * g + r;
        int bl = m >> 13, s = m & 8191;
        size_t bh = (size_t)bl * NHEADS + h;
        dst[(bh * SEQ + s) * HDIM + d] = f2bf(a[r] + bval);
      }
    }
  }
}

// ---------------------------------------------------------------------------
// vws [bh][s][d] -> vt [bh][d][s], 64x64 LDS tiles, fully coalesced.
__global__ __launch_bounds__(256) void vt_transpose(
    const unsigned short* __restrict__ vws, unsigned short* __restrict__ vt) {
  __shared__ unsigned short tile[64][72];
  int bid = blockIdx.x;
  int st = bid & 127;
  int bh = bid >> 7;
  int t = threadIdx.x;
  const unsigned short* src = vws + ((size_t)bh * SEQ + st * 64) * HDIM;
#pragma unroll
  for (int i = 0; i < 2; ++i) {
    int idx = t + i * 256;
    int r = idx >> 3, c = idx & 7;
    uint4 v = *(const uint4*)(src + r * HDIM + c * 8);
    *(uint4*)&tile[r][c * 8] = v;
  }
  __syncthreads();
  unsigned short* dst = vt + (size_t)bh * ((size_t)HDIM * SEQ) + st * 64;
#pragma unroll
  for (int i = 0; i < 2; ++i) {
    int idx = t + i * 256;
    int d = idx >> 3, c = idx & 7;
    ushort4 a, b;
    a.x = tile[c * 8 + 0][d]; a.y = tile[c * 8 + 1][d];
    a.z = tile[c * 8 + 2][d]; a.w = tile[c * 8 + 3][d];
    b.x = tile[c * 8 + 4][d]; b.y = tile[c * 8 + 5][d];
    b.z = tile[c * 8 + 6][d]; b.w = tile[c * 8 + 7][d];
    *(ushort4*)(dst + (size_t)d * SEQ + c * 8) = a;
    *(ushort4*)(dst + (size_t)d * SEQ + c * 8 + 4) = b;
  }
}

// ---------------------------------------------------------------------------
// MFMA attention — exact R4 kernel. Block = (b,h,n). 512 thr = 8 waves.
__global__ __launch_bounds__(512, 2) void attn_kernel(
    const unsigned short* __restrict__ qws, const unsigned short* __restrict__ kws,
    const unsigned short* __restrict__ vt, const unsigned short* __restrict__ posq,
    const unsigned short* __restrict__ posk, unsigned short* __restrict__ ctx) {
  extern __shared__ char smem[];
  int* iLUT = (int*)(smem + LUT_OFF);
  unsigned short* C2P = (unsigned short*)(smem + C2P_OFF);
  unsigned short* Tl = (unsigned short*)(smem + T_OFF);

  const int tid = threadIdx.x;
  const int wave = tid >> 6;
  const int lane = tid & 63;
  const int l15 = lane & 15;
  const int g = lane >> 4;
  const int qs = wave << 4;

  const int n = blockIdx.x & 63;
  const int bh = blockIdx.x >> 6;
  const int h = bh % NHEADS;
  const int b = bh / NHEADS;

  const unsigned short* qsrc = qws + ((size_t)bh * SEQ + n * BSZ) * HDIM;
  const unsigned short* kbh = kws + (size_t)bh * SEQ * HDIM;
  const unsigned short* vtbh = vt + (size_t)bh * ((size_t)HDIM * SEQ);
  const unsigned short* pqh = posq + (size_t)h * PBUCK * HDIM;
  const unsigned short* pkh = posk + (size_t)h * PBUCK * HDIM;

  // ---- phase 0: stage Q, posk half 0, fill LUT
  for (int idx = tid; idx < 128 * 8; idx += 512) {
    int row = idx >> 3, c = idx & 7;
    uint4 v = *(const uint4*)(qsrc + row * HDIM + c * 8);
    *(uint4*)(smem + Q_OFF + row * 128 + ((c * 16) ^ ((row & 7) << 4))) = v;
  }
  for (int idx = tid; idx < 192 * 8; idx += 512) {
    int row = idx >> 3, c = idx & 7;
    uint4 v = *(const uint4*)(pkh + row * HDIM + c * 8);
    *(uint4*)(smem + PKH_OFF + row * 128 + ((c * 16) ^ ((row & 7) << 4))) = v;
  }
  if (tid < 511) iLUT[tid] = bucket_idx(tid - 383);
  __syncthreads();

  bf16x8 qf0 = ldfrag(smem, Q_OFF, qs + l15, 128, 0, g);
  bf16x8 qf1 = ldfrag(smem, Q_OFF, qs + l15, 128, 1, g);

  // ---- phase 1: C2P_all[q][p] = Q . posk^T  (two halves of 192 p)
#pragma unroll
  for (int half = 0; half < 2; ++half) {
    if (half) {
      __syncthreads();
      for (int idx = tid; idx < 192 * 8; idx += 512) {
        int row = idx >> 3, c = idx & 7;
        uint4 v = *(const uint4*)(pkh + (192 + row) * HDIM + c * 8);
        *(uint4*)(smem + PKH_OFF + row * 128 + ((c * 16) ^ ((row & 7) << 4))) = v;
      }
      __syncthreads();
    }
    for (int ntl = 0; ntl < 12; ++ntl) {
      bf16x8 b0 = ldfrag(smem, PKH_OFF, 16 * ntl + l15, 128, 0, g);
      bf16x8 b1 = ldfrag(smem, PKH_OFF, 16 * ntl + l15, 128, 1, g);
      f32x4 c = {0.f, 0.f, 0.f, 0.f};
      c = MFMA16(qf0, b0, c);
      c = MFMA16(qf1, b1, c);
      int p = half * 192 + 16 * ntl + l15;
#pragma unroll
      for (int r = 0; r < 4; ++r)
        C2P[(qs + 4 * g + r) * 392 + p] = f2bf(c[r]);
    }
  }
  __syncthreads();

  // ---- phase 2: S accumulators init with gathered c2p
  f32x4 acc[24];
#pragma unroll
  for (int t = 0; t < 24; ++t) acc[t] = (f32x4){0.f, 0.f, 0.f, 0.f};
  {
    const int qrow = qs + l15;
    const unsigned short* c2pRow = C2P + qrow * 392;
    const int dbase = qrow - 4 * g + 383;
#pragma unroll
    for (int t = 0; t < 24; ++t) {
#pragma unroll
      for (int r = 0; r < 4; ++r) {
        int idx = iLUT[dbase - 16 * t - r];
        acc[t][r] += bf2f(c2pRow[idx]);
      }
    }
  }
  __syncthreads();  // C2P dead

  // ---- phase 3: stage K and posq (zero-fill outside [0,SEQ))
  for (int idx = tid; idx < 384 * 8; idx += 512) {
    int row = idx >> 3, c = idx & 7;
    int ks = n * BSZ - BSZ + row;
    uint4 v = make_uint4(0u, 0u, 0u, 0u);
    if (ks >= 0 && ks < SEQ) v = *(const uint4*)(kbh + (size_t)ks * HDIM + c * 8);
    *(uint4*)(smem + K_OFF + row * 128 + ((c * 16) ^ ((row & 7) << 4))) = v;
  }
  for (int idx = tid; idx < 384 * 8; idx += 512) {
    int row = idx >> 3, c = idx & 7;
    uint4 v = *(const uint4*)(pqh + row * HDIM + c * 8);
    *(uint4*)(smem + PQ_OFF + row * 128 + ((c * 16) ^ ((row & 7) << 4))) = v;
  }
  __syncthreads();

  // ---- phase 4: p2c, 12 subtiles of 32 kwin
#pragma unroll
  for (int s = 0; s < 12; ++s) {
    const int lo = iLUT[352 - 32 * s];
    const int hi = iLUT[510 - 32 * s];
    const int ntiles = ((hi - lo + 1) + 15) >> 4;
    for (int tl = wave; tl < 2 * ntiles; tl += 8) {
      int mt = tl & 1, ntl = tl >> 1;
      bf16x8 a0 = ldfrag(smem, K_OFF, 32 * s + 16 * mt + l15, 128, 0, g);
      bf16x8 a1 = ldfrag(smem, K_OFF, 32 * s + 16 * mt + l15, 128, 1, g);
      int prow = lo + 16 * ntl + l15;
      prow = prow > 383 ? 383 : prow;
      bf16x8 b0 = ldfrag(smem, PQ_OFF, prow, 128, 0, g);
      bf16x8 b1 = ldfrag(smem, PQ_OFF, prow, 128, 1, g);
      f32x4 c = {0.f, 0.f, 0.f, 0.f};
      c = MFMA16(a0, b0, c);
      c = MFMA16(a1, b1, c);
#pragma unroll
      for (int r = 0; r < 4; ++r)
        Tl[(16 * mt + 4 * g + r) * 184 + 16 * ntl + l15] = f2bf(c[r]);
    }
    __syncthreads();
    {
      const int dbase2 = qs + l15 - 32 * s - 4 * g + 383;
#pragma unroll
      for (int tt = 0; tt < 2; ++tt) {
#pragma unroll
        for (int r = 0; r < 4; ++r) {
          int idx = iLUT[dbase2 - 16 * tt - r];
          acc[2 * s + tt][r] += bf2f(Tl[(16 * tt + 4 * g + r) * 184 + idx - lo]);
        }
      }
    }
    __syncthreads();
  }

  // ---- phase 5: QK^T accumulate (A = K rows, B = Q^T)
#pragma unroll
  for (int t = 0; t < 24; ++t) {
    bf16x8 a0 = ldfrag(smem, K_OFF, 16 * t + l15, 128, 0, g);
    bf16x8 a1 = ldfrag(smem, K_OFF, 16 * t + l15, 128, 1, g);
    acc[t] = MFMA16(a0, qf0, acc[t]);
    acc[t] = MFMA16(a1, qf1, acc[t]);
  }
  __syncthreads();  // posq region dead; about to become Vt

  // ---- phase 6: stage Vt (zero-fill outside [0,SEQ))
  for (int idx = tid; idx < 64 * 48; idx += 512) {
    int row = idx / 48, c = idx - row * 48;
    int col0 = n * BSZ - BSZ + c * 8;
    uint4 v = make_uint4(0u, 0u, 0u, 0u);
    if (col0 >= 0 && col0 < SEQ)
      v = *(const uint4*)(vtbh + (size_t)row * SEQ + col0);
    *(uint4*)(smem + VT_OFF + row * 768 + ((c * 16) ^ ((row & 7) << 4))) = v;
  }

  // ---- phase 7: softmax (in-register; q = qs + l15 fixed per lane)
  float m = -1e30f;
#pragma unroll
  for (int t = 0; t < 24; ++t)
#pragma unroll
    for (int r = 0; r < 4; ++r) m = fmaxf(m, acc[t][r]);
  m = fmaxf(m, __shfl_xor(m, 16));
  m = fmaxf(m, __shfl_xor(m, 32));
  float sum = 0.f;
#pragma unroll
  for (int t = 0; t < 24; ++t)
#pragma unroll
    for (int r = 0; r < 4; ++r) {
      float p = exp2f((acc[t][r] - m) * 0.10411790f);  // /sqrt(192) * log2e
      acc[t][r] = p;
      sum += p;
    }
  sum += __shfl_xor(sum, 16);
  sum += __shfl_xor(sum, 32);
  float inv = 1.0f / sum;

  bf16x8 pa[12];
#pragma unroll
  for (int kt = 0; kt < 12; ++kt) {
    union { bf16x8 v; unsigned short u[8]; } w;
#pragma unroll
    for (int j = 0; j < 4; ++j) w.u[j] = f2bf(acc[2 * kt][j] * inv);
#pragma unroll
    for (int j = 0; j < 4; ++j) w.u[4 + j] = f2bf(acc[2 * kt + 1][j] * inv);
    pa[kt] = w.v;
  }
  __syncthreads();  // Vt staged

  // ---- phase 8: PV, write ctx bf16
  unsigned short* ctxg = ctx + ((size_t)b * SEQ + n * BSZ) * HID + h * HDIM;
#pragma unroll
  for (int nt = 0; nt < 4; ++nt) {
    f32x4 o = {0.f, 0.f, 0.f, 0.f};
#pragma unroll
    for (int kt = 0; kt < 12; ++kt) {
      bf16x8 bv = ldfrag(smem, VT_OFF, 16 * nt + l15, 768, kt, g);
      o = MFMA16(pa[kt], bv, o);
    }
#pragma unroll
    for (int r = 0; r < 4; ++r) {
      size_t off = (size_t)(qs + 4 * g + r) * HID + 16 * nt + l15;
      ctxg[off] = f2bf(o[r]);
    }
  }
}

// ---------------------------------------------------------------------------
// Fused out-projection + bias + residual + LayerNorm.
// Block = 64 rows x 768 cols. 512 thr = 8 waves; wave w owns cols [96w,96w+96).
__global__ __launch_bounds__(512) void out_ln(
    const unsigned short* __restrict__ ctx, const unsigned short* __restrict__ WoT,
    const float* __restrict__ bo, const float* __restrict__ hidden,
    const float* __restrict__ lns, const float* __restrict__ lnb,
    float* __restrict__ out) {
  extern __shared__ char smem[];
  unsigned short* Au = (unsigned short*)(smem + OL_AU);
  unsigned short* Bu = (unsigned short*)(smem + OL_BU);
  float* red1 = (float*)(smem + OL_R1);
  float* red2 = (float*)(smem + OL_R2);
  float* muA = (float*)(smem + OL_MU);
  float* rsA = (float*)(smem + OL_RS);

  const int t = threadIdx.x;
  const int lane = t & 63;
  const int l15 = lane & 15, g = lane >> 4;
  const int w = t >> 6;
  const int m0 = blockIdx.x * 64;

  f32x4 acc[4][6];
#pragma unroll
  for (int mt = 0; mt < 4; ++mt)
#pragma unroll
    for (int nt = 0; nt < 6; ++nt) acc[mt][nt] = (f32x4){0.f, 0.f, 0.f, 0.f};

  for (int k0 = 0; k0 < HID; k0 += 32) {
    if (t < 256) {
      int r = t >> 2, c = t & 3;
      uint4 v = *(const uint4*)(ctx + (size_t)(m0 + r) * HID + k0 + c * 8);
      *(uint4*)(Au + r * 40 + c * 8) = v;
    }
#pragma unroll
    for (int i = 0; i < 6; ++i) {
      int idx = t + i * 512;
      int nrow = idx >> 2, c = idx & 3;
      uint4 v = *(const uint4*)(WoT + (size_t)nrow * HID + k0 + c * 8);
      *(uint4*)(Bu + nrow * 40 + c * 8) = v;
    }
    __syncthreads();
    bf16x8 af[4];
#pragma unroll
    for (int mt = 0; mt < 4; ++mt) af[mt] = olfrag(Au, mt * 16 + l15, g);
#pragma unroll
    for (int nt = 0; nt < 6; ++nt) {
      bf16x8 bf = olfrag(Bu, w * 96 + nt * 16 + l15, g);
#pragma unroll
      for (int mt = 0; mt < 4; ++mt)
        acc[mt][nt] = MFMA16(af[mt], bf, acc[mt][nt]);
    }
    __syncthreads();
  }

  // bias + residual; per-lane row partials
  float psum[4][4] = {};
  float psq[4][4] = {};
#pragma unroll
  for (int nt = 0; nt < 6; ++nt) {
    int gn = w * 96 + nt * 16 + l15;
    float bval = bo[gn];
#pragma unroll
    for (int mt = 0; mt < 4; ++mt) {
#pragma unroll
      for (int r = 0; r < 4; ++r) {
        int gm = m0 + mt * 16 + 4 * g + r;
        float v = acc[mt][nt][r] + bval + hidden[(size_t)gm * HID + gn];
        acc[mt][nt][r] = v;
        psum[mt][r] += v;
        psq[mt][r] += v * v;
      }
    }
  }
#pragma unroll
  for (int o = 1; o < 16; o <<= 1) {
#pragma unroll
    for (int mt = 0; mt < 4; ++mt)
#pragma unroll
      for (int r = 0; r < 4; ++r) {
        psum[mt][r] += __shfl_xor(psum[mt][r], o);
        psq[mt][r] += __shfl_xor(psq[mt][r], o);
      }
  }
  if (l15 == 0) {
#pragma unroll
    for (int mt = 0; mt < 4; ++mt)
#pragma unroll
      for (int r = 0; r < 4; ++r) {
        red1[(mt * 16 + 4 * g + r) * 8 + w] = psum[mt][r];
        red2[(mt * 16 + 4 * g + r) * 8 + w] = psq[mt][r];
      }
  }
  __syncthreads();
  if (t < 64) {
    float s = 0.f, s2 = 0.f;
#pragma unroll
    for (int i = 0; i < 8; ++i) {
      s += red1[t * 8 + i];
      s2 += red2[t * 8 + i];
    }
    float mu = s * (1.0f / 768.0f);
    float var = s2 * (1.0f / 768.0f) - mu * mu;
    muA[t] = mu;
    rsA[t] = 1.0f / sqrtf(var + 1e-7f);
  }
  __syncthreads();
#pragma unroll
  for (int nt = 0; nt < 6; ++nt) {
    int gn = w * 96 + nt * 16 + l15;
    float sc = lns[gn], bi = lnb[gn];
#pragma unroll
    for (int mt = 0; mt < 4; ++mt) {
#pragma unroll
      for (int r = 0; r < 4; ++r) {
        int lm = mt * 16 + 4 * g + r;
        float v = (acc[mt][nt][r] - muA[lm]) * rsA[lm] * sc + bi;
        out[(size_t)(m0 + lm) * HID + gn] = v;
      }
    }
  }
}

extern "C" void kernel_launch(void* const* d_in, const int* in_sizes, int n_in,
                              void* d_out, int out_size, void* d_ws,
                              size_t ws_size, hipStream_t stream) {
  (void)in_sizes; (void)n_in; (void)out_size; (void)ws_size;
  const float* hidden = (const float*)d_in[0];
  const float* relpos = (const float*)d_in[1];
  const float* Wq = (const float*)d_in[2];
  const float* bq = (const float*)d_in[3];
  const float* Wk = (const float*)d_in[4];
  const float* bk = (const float*)d_in[5];
  const float* Wv = (const float*)d_in[6];
  const float* bv = (const float*)d_in[7];
  const float* Wo = (const float*)d_in[8];
  const float* bo = (const float*)d_in[9];
  const float* lns = (const float*)d_in[10];
  const float* lnb = (const float*)d_in[11];
  float* out = (float*)d_out;

  // Workspace (ushort units): q | k | vt | ctx | posq | posk | WqkvT(=WoT)
  // vws (coalesced v) aliases ctx: dead once vt_transpose completes, and ctx
  // is only written by attn afterwards.
  unsigned short* ws = (unsigned short*)d_ws;
  const size_t QE = (size_t)48 * SEQ * HDIM;  // 25,165,824
  unsigned short* qws = ws;
  unsigned short* kws = qws + QE;
  unsigned short* vt = kws + QE;
  unsigned short* ctx = vt + QE;
  unsigned short* vws = ctx;  // alias
  unsigned short* posq = ctx + QE;
  unsigned short* posk = posq + (size_t)NHEADS * PBUCK * HDIM;
  unsigned short* WqkvT = posk + (size_t)NHEADS * PBUCK * HDIM;
  unsigned short* WoT = WqkvT;  // alias: WqkvT dead before conv of Wo

  static bool attrib_set = false;
  if (!attrib_set) {
    hipFuncSetAttribute((const void*)attn_kernel,
                        hipFuncAttributeMaxDynamicSharedMemorySize, SMEM_ATTN);
    hipFuncSetAttribute((const void*)out_ln,
                        hipFuncAttributeMaxDynamicSharedMemorySize, SMEM_OL);
    attrib_set = true;
  }

  conv_wt<<<dim3(12, 12, 3), 256, 0, stream>>>(Wq, Wk, Wv, WqkvT);
  pos_gemm<<<dim3(8, 24), 256, 0, stream>>>(relpos, Wq, Wk, bq, bk, posq, posk);
  qkv_mfma<<<dim3(18, 256), 256, 0, stream>>>(hidden, WqkvT, bq, bk, bv, qws,
                                              kws, vws);
  vt_transpose<<<6144, 256, 0, stream>>>(vws, vt);
  conv_wt<<<dim3(12, 12, 1), 256, 0, stream>>>(Wo, Wo, Wo, WoT);
  attn_kernel<<<3072, 512, SMEM_ATTN, stream>>>(qws, kws, vt, posq, posk, ctx);
  out_ln<<<512, 512, SMEM_OL, stream>>>(ctx, WoT, bo, hidden, lns, lnb, out);
}

// Round 10
// 746.627 us; speedup vs baseline: 3.2065x; 1.0930x over previous
//
#include <hip/hip_runtime.h>
#include <math.h>

// ---------------------------------------------------------------------------
// LocalSlidingWindow_DisentangledAttention — Round 10:
//  - hbf_conv: hidden fp32 -> bf16 once (qkv A re-read halves; L3-resident)
//  - qkv_mfma: A staged from hbf (uint4, no cvt VALU)
//  - attn: R4-proven kernel; phase-6 transposes V during LDS staging from
//    coalesced vws [s][d] (vt buffer + vt_transpose kernel deleted)
//  - conv_wt: one launch for Wq/Wk/Wv/Wo
//  - out_ln: fused out-projection + LayerNorm (unchanged from R9)
// Workspace = 207,618,048 B (exactly the proven R2 footprint).
// ---------------------------------------------------------------------------

#define NHEADS 12
#define HDIM   64
#define SEQ    8192
#define HID    768
#define BSZ    128
#define WIN    384
#define PBUCK  512

typedef __attribute__((ext_vector_type(8))) short bf16x8;
typedef __attribute__((ext_vector_type(4))) float f32x4;
#define MFMA16(a, b, c) __builtin_amdgcn_mfma_f32_16x16x32_bf16((a), (b), (c), 0, 0, 0)

// attn LDS byte map (dynamic, 155136 total) — R4 layout
#define C2P_OFF 0        // [128][392] bf16 = 100352   (phase 1-2)
#define K_OFF   0        // [384][64]  bf16 = 49152    (phase 3+)
#define PQ_OFF  49152    // [384][64]  bf16 = 49152    (phase 3-4)
#define VT_OFF  49152    // [64][384]  bf16 = 49152    (PV phase)
#define T_OFF   100352   // [32][184]  bf16 = 11776
#define Q_OFF   112128   // [128][64]  bf16 = 16384
#define PKH_OFF 128512   // [192][64]  bf16 = 24576
#define LUT_OFF 153088   // [511] int  = 2044
#define SMEM_ATTN 155136

// out_ln LDS byte map (dynamic, 71168)
#define OL_AU 0          // [64][40] bf16 = 5120
#define OL_BU 5120       // [768][40] bf16 = 61440
#define OL_R1 66560      // [64][8] f32 = 2048
#define OL_R2 68608      // [64][8] f32 = 2048
#define OL_MU 70656      // [64] f32
#define OL_RS 70912      // [64] f32
#define SMEM_OL 71168

__device__ __forceinline__ unsigned short f2bf(float f) {
  unsigned int x = __builtin_bit_cast(unsigned int, f);
  unsigned int r = (x + 0x7FFFu + ((x >> 16) & 1u)) >> 16;
  return (unsigned short)r;
}
__device__ __forceinline__ float bf2f(unsigned short u) {
  unsigned int x = ((unsigned int)u) << 16;
  return __builtin_bit_cast(float, x);
}

// idx(rel) for rel in [-383, 127]
__device__ __forceinline__ int bucket_idx(int rel) {
  if (rel >= -128) return rel + 256;
  float a = (float)(-rel);
  float t = logf(a * (1.0f / 128.0f));
  t = t / 0.6892332813f;
  t = t * 127.0f;
  int lp = (int)(ceilf(t) + 128.0f);
  int r = 256 - lp;
  return r < 0 ? 0 : r;
}

// Fragment load from swizzled row-major bf16 LDS tile.
__device__ __forceinline__ bf16x8 ldfrag(const char* sm, int byteBase, int row,
                                         int rowBytes, int slice, int g) {
  const int swz = (row & 7) << 4;
  const char* p = sm + byteBase + row * rowBytes;
  union { bf16x8 v; uint2 u2[2]; } w;
  w.u2[0] = *(const uint2*)(p + (((slice << 6) + (g << 3)) ^ swz));
  w.u2[1] = *(const uint2*)(p + (((slice << 6) + 32 + (g << 3)) ^ swz));
  return w.v;
}

// Fragment from padded (40-ushort rows, no swizzle) LDS tile for out_ln.
__device__ __forceinline__ bf16x8 olfrag(const unsigned short* base, int row,
                                         int g) {
  const unsigned short* p = base + row * 40 + 4 * g;
  union { bf16x8 v; uint2 u2[2]; } w;
  w.u2[0] = *(const uint2*)(p);
  w.u2[1] = *(const uint2*)(p + 16);
  return w.v;
}

// ---------------------------------------------------------------------------
// hidden fp32 -> bf16 (one pass; hbf aliases ctx region, dead before attn)
__global__ __launch_bounds__(256) void hbf_conv(const float* __restrict__ src,
                                                unsigned short* __restrict__ dst) {
  size_t i = ((size_t)blockIdx.x * 256 + threadIdx.x) * 8;
  float4 a = *(const float4*)(src + i);
  float4 b = *(const float4*)(src + i + 4);
  union { uint4 q; unsigned short u[8]; } w;
  w.u[0] = f2bf(a.x); w.u[1] = f2bf(a.y); w.u[2] = f2bf(a.z); w.u[3] = f2bf(a.w);
  w.u[4] = f2bf(b.x); w.u[5] = f2bf(b.y); w.u[6] = f2bf(b.z); w.u[7] = f2bf(b.w);
  *(uint4*)(dst + i) = w.q;
}

// Weight transpose fp32 -> bf16: Wt[z*768 + n][k] = W_z[k][n], z = 0..3
__global__ __launch_bounds__(256) void conv_wt(const float* __restrict__ W0,
                                               const float* __restrict__ W1,
                                               const float* __restrict__ W2,
                                               const float* __restrict__ W3,
                                               unsigned short* __restrict__ Wt) {
  __shared__ float tile[64][65];
  int bx = blockIdx.x, by = blockIdx.y, z = blockIdx.z;
  const float* W = (z == 0) ? W0 : (z == 1 ? W1 : (z == 2 ? W2 : W3));
  int t = threadIdx.x;
  int c = t & 63, r0 = (t >> 6) * 16;
#pragma unroll
  for (int rr = 0; rr < 16; ++rr)
    tile[r0 + rr][c] = W[(size_t)(by * 64 + r0 + rr) * HID + bx * 64 + c];
  __syncthreads();
#pragma unroll
  for (int rr = 0; rr < 16; ++rr) {
    int nw = r0 + rr;
    Wt[((size_t)z * HID + bx * 64 + nw) * HID + by * 64 + c] = f2bf(tile[c][nw]);
  }
}

// Positional projection (fp32 math) -> bf16 posq/posk [h][512][64]
__global__ __launch_bounds__(256) void pos_gemm(
    const float* __restrict__ relpos, const float* __restrict__ Wq,
    const float* __restrict__ Wk, const float* __restrict__ bq,
    const float* __restrict__ bk, unsigned short* __restrict__ posq,
    unsigned short* __restrict__ posk) {
  __shared__ float At[32][68];
  __shared__ float Bs[32][68];
  int m0 = blockIdx.x * 64;
  int n0 = blockIdx.y * 64;
  int w = n0 / HID;
  int nc0 = n0 % HID;
  const float* W = (w == 0) ? Wq : Wk;
  const float* bias = (w == 0) ? bq : bk;
  int t = threadIdx.x;
  int tx = t & 15, ty = t >> 4;
  float acc[4][4] = {};
  for (int k0 = 0; k0 < HID; k0 += 32) {
#pragma unroll
    for (int u = 0; u < 2; ++u) {
      int f = t * 2 + u;
      int r = f >> 3, c4 = f & 7;
      float4 av = *(const float4*)(relpos + (size_t)(m0 + r) * HID + k0 + c4 * 4);
      At[c4 * 4 + 0][r] = av.x; At[c4 * 4 + 1][r] = av.y;
      At[c4 * 4 + 2][r] = av.z; At[c4 * 4 + 3][r] = av.w;
    }
#pragma unroll
    for (int u = 0; u < 2; ++u) {
      int f = t * 2 + u;
      int kk = f >> 4, c4 = f & 15;
      float4 bv4 = *(const float4*)(W + (size_t)(k0 + kk) * HID + nc0 + c4 * 4);
      *(float4*)&Bs[kk][c4 * 4] = bv4;
    }
    __syncthreads();
#pragma unroll
    for (int kk = 0; kk < 32; ++kk) {
      float4 a4 = *(const float4*)&At[kk][ty * 4];
      float4 b4 = *(const float4*)&Bs[kk][tx * 4];
      float av[4] = {a4.x, a4.y, a4.z, a4.w};
      float bvv[4] = {b4.x, b4.y, b4.z, b4.w};
#pragma unroll
      for (int i = 0; i < 4; ++i)
#pragma unroll
        for (int jj = 0; jj < 4; ++jj) acc[i][jj] += av[i] * bvv[jj];
    }
    __syncthreads();
  }
  int h = nc0 >> 6;
  unsigned short* dst = (w == 0) ? posq : posk;
#pragma unroll
  for (int i = 0; i < 4; ++i) {
    int p = m0 + ty * 4 + i;
    ushort4 o;
    o.x = f2bf(acc[i][0] + bias[nc0 + tx * 4 + 0]);
    o.y = f2bf(acc[i][1] + bias[nc0 + tx * 4 + 1]);
    o.z = f2bf(acc[i][2] + bias[nc0 + tx * 4 + 2]);
    o.w = f2bf(acc[i][3] + bias[nc0 + tx * 4 + 3]);
    *(ushort4*)(dst + ((size_t)h * PBUCK + p) * HDIM + tx * 4) = o;
  }
}

// ---------------------------------------------------------------------------
// QKV projection, bf16 MFMA. Tile 128x128, BK=64, 256 thr = 4 waves (2x2).
// A staged from pre-converted hbf (uint4, no cvt). All outputs [bh][s][d].
__global__ __launch_bounds__(256) void qkv_mfma(
    const unsigned short* __restrict__ hbf, const unsigned short* __restrict__ Wt,
    const float* __restrict__ bq, const float* __restrict__ bk,
    const float* __restrict__ bv, unsigned short* __restrict__ qws,
    unsigned short* __restrict__ kws, unsigned short* __restrict__ vws) {
  __shared__ unsigned short As[8192];
  __shared__ unsigned short Bs[8192];
  const int t = threadIdx.x;
  const int lane = t & 63;
  const int l15 = lane & 15, g = lane >> 4;
  const int wave = t >> 6;
  const int wy = wave >> 1, wx = wave & 1;
  const int n0 = blockIdx.x * 128;
  const int m0 = blockIdx.y * 128;

  f32x4 acc[4][4];
#pragma unroll
  for (int i = 0; i < 4; ++i)
#pragma unroll
    for (int j = 0; j < 4; ++j) acc[i][j] = (f32x4){0.f, 0.f, 0.f, 0.f};

  for (int k0 = 0; k0 < HID; k0 += 64) {
#pragma unroll
    for (int i = 0; i < 4; ++i) {
      int c = t + i * 256;
      int row = c >> 3, cx = c & 7;
      uint4 v = *(const uint4*)(hbf + (size_t)(m0 + row) * HID + k0 + cx * 8);
      *(uint4*)((char*)As + row * 128 + ((cx * 16) ^ ((row & 7) << 4))) = v;
    }
#pragma unroll
    for (int i = 0; i < 4; ++i) {
      int c = t + i * 256;
      int row = c >> 3, cx = c & 7;
      uint4 v = *(const uint4*)(Wt + (size_t)(n0 + row) * HID + k0 + cx * 8);
      *(uint4*)((char*)Bs + row * 128 + ((cx * 16) ^ ((row & 7) << 4))) = v;
    }
    __syncthreads();
    bf16x8 af[4][2], bf[4][2];
#pragma unroll
    for (int mt = 0; mt < 4; ++mt) {
      int row = wy * 64 + mt * 16 + l15;
      const char* p = (const char*)As + row * 128;
      int swz = (row & 7) << 4;
#pragma unroll
      for (int s = 0; s < 2; ++s)
        af[mt][s] = *(const bf16x8*)(p + ((s * 64 + g * 16) ^ swz));
    }
#pragma unroll
    for (int nt = 0; nt < 4; ++nt) {
      int row = wx * 64 + nt * 16 + l15;
      const char* p = (const char*)Bs + row * 128;
      int swz = (row & 7) << 4;
#pragma unroll
      for (int s = 0; s < 2; ++s)
        bf[nt][s] = *(const bf16x8*)(p + ((s * 64 + g * 16) ^ swz));
    }
#pragma unroll
    for (int mt = 0; mt < 4; ++mt)
#pragma unroll
      for (int nt = 0; nt < 4; ++nt) {
        acc[mt][nt] = MFMA16(af[mt][0], bf[nt][0], acc[mt][nt]);
        acc[mt][nt] = MFMA16(af[mt][1], bf[nt][1], acc[mt][nt]);
      }
    __syncthreads();
  }

  const int w = n0 / HID;  // 0:q 1:k 2:v
  const float* bias = (w == 0) ? bq : (w == 1 ? bk : bv);
  unsigned short* dst = (w == 0) ? qws : (w == 1 ? kws : vws);
#pragma unroll
  for (int nt = 0; nt < 4; ++nt) {
    int gn = n0 + wx * 64 + nt * 16 + l15;
    int nc = gn - w * HID;
    int h = nc >> 6, d = nc & 63;
    float bval = bias[nc];
#pragma unroll
    for (int mt = 0; mt < 4; ++mt) {
      f32x4 a = acc[mt][nt];
#pragma unroll
      for (int r = 0; r < 4; ++r) {
        int m = m0 + wy * 64 + mt * 16 + 4 * g + r;
        int bl = m >> 13, s = m & 8191;
        size_t bh = (size_t)bl * NHEADS + h;
        dst[(bh * SEQ + s) * HDIM + d] = f2bf(a[r] + bval);
      }
    }
  }
}

// ---------------------------------------------------------------------------
// MFMA attention — R4 kernel; phase 6 transposes V from vws [s][d] in-staging.
__global__ __launch_bounds__(512, 2) void attn_kernel(
    const unsigned short* __restrict__ qws, const unsigned short* __restrict__ kws,
    const unsigned short* __restrict__ vws, const unsigned short* __restrict__ posq,
    const unsigned short* __restrict__ posk, unsigned short* __restrict__ ctx) {
  extern __shared__ char smem[];
  int* iLUT = (int*)(smem + LUT_OFF);
  unsigned short* C2P = (unsigned short*)(smem + C2P_OFF);
  unsigned short* Tl = (unsigned short*)(smem + T_OFF);

  const int tid = threadIdx.x;
  const int wave = tid >> 6;
  const int lane = tid & 63;
  const int l15 = lane & 15;
  const int g = lane >> 4;
  const int qs = wave << 4;

  const int n = blockIdx.x & 63;
  const int bh = blockIdx.x >> 6;
  const int h = bh % NHEADS;
  const int b = bh / NHEADS;

  const unsigned short* qsrc = qws + ((size_t)bh * SEQ + n * BSZ) * HDIM;
  const unsigned short* kbh = kws + (size_t)bh * SEQ * HDIM;
  const unsigned short* vbh = vws + (size_t)bh * SEQ * HDIM;
  const unsigned short* pqh = posq + (size_t)h * PBUCK * HDIM;
  const unsigned short* pkh = posk + (size_t)h * PBUCK * HDIM;

  // ---- phase 0: stage Q, posk half 0, fill LUT
  for (int idx = tid; idx < 128 * 8; idx += 512) {
    int row = idx >> 3, c = idx & 7;
    uint4 v = *(const uint4*)(qsrc + row * HDIM + c * 8);
    *(uint4*)(smem + Q_OFF + row * 128 + ((c * 16) ^ ((row & 7) << 4))) = v;
  }
  for (int idx = tid; idx < 192 * 8; idx += 512) {
    int row = idx >> 3, c = idx & 7;
    uint4 v = *(const uint4*)(pkh + row * HDIM + c * 8);
    *(uint4*)(smem + PKH_OFF + row * 128 + ((c * 16) ^ ((row & 7) << 4))) = v;
  }
  if (tid < 511) iLUT[tid] = bucket_idx(tid - 383);
  __syncthreads();

  bf16x8 qf0 = ldfrag(smem, Q_OFF, qs + l15, 128, 0, g);
  bf16x8 qf1 = ldfrag(smem, Q_OFF, qs + l15, 128, 1, g);

  // ---- phase 1: C2P_all[q][p] = Q . posk^T  (two halves of 192 p)
#pragma unroll
  for (int half = 0; half < 2; ++half) {
    if (half) {
      __syncthreads();
      for (int idx = tid; idx < 192 * 8; idx += 512) {
        int row = idx >> 3, c = idx & 7;
        uint4 v = *(const uint4*)(pkh + (192 + row) * HDIM + c * 8);
        *(uint4*)(smem + PKH_OFF + row * 128 + ((c * 16) ^ ((row & 7) << 4))) = v;
      }
      __syncthreads();
    }
    for (int ntl = 0; ntl < 12; ++ntl) {
      bf16x8 b0 = ldfrag(smem, PKH_OFF, 16 * ntl + l15, 128, 0, g);
      bf16x8 b1 = ldfrag(smem, PKH_OFF, 16 * ntl + l15, 128, 1, g);
      f32x4 c = {0.f, 0.f, 0.f, 0.f};
      c = MFMA16(qf0, b0, c);
      c = MFMA16(qf1, b1, c);
      int p = half * 192 + 16 * ntl + l15;
#pragma unroll
      for (int r = 0; r < 4; ++r)
        C2P[(qs + 4 * g + r) * 392 + p] = f2bf(c[r]);
    }
  }
  __syncthreads();

  // ---- phase 2: S accumulators init with gathered c2p
  f32x4 acc[24];
#pragma unroll
  for (int t = 0; t < 24; ++t) acc[t] = (f32x4){0.f, 0.f, 0.f, 0.f};
  {
    const int qrow = qs + l15;
    const unsigned short* c2pRow = C2P + qrow * 392;
    const int dbase = qrow - 4 * g + 383;
#pragma unroll
    for (int t = 0; t < 24; ++t) {
#pragma unroll
      for (int r = 0; r < 4; ++r) {
        int idx = iLUT[dbase - 16 * t - r];
        acc[t][r] += bf2f(c2pRow[idx]);
      }
    }
  }
  __syncthreads();  // C2P dead

  // ---- phase 3: stage K and posq (zero-fill outside [0,SEQ))
  for (int idx = tid; idx < 384 * 8; idx += 512) {
    int row = idx >> 3, c = idx & 7;
    int ks = n * BSZ - BSZ + row;
    uint4 v = make_uint4(0u, 0u, 0u, 0u);
    if (ks >= 0 && ks < SEQ) v = *(const uint4*)(kbh + (size_t)ks * HDIM + c * 8);
    *(uint4*)(smem + K_OFF + row * 128 + ((c * 16) ^ ((row & 7) << 4))) = v;
  }
  for (int idx = tid; idx < 384 * 8; idx += 512) {
    int row = idx >> 3, c = idx & 7;
    uint4 v = *(const uint4*)(pqh + row * HDIM + c * 8);
    *(uint4*)(smem + PQ_OFF + row * 128 + ((c * 16) ^ ((row & 7) << 4))) = v;
  }
  __syncthreads();

  // ---- phase 4: p2c, 12 subtiles of 32 kwin
#pragma unroll
  for (int s = 0; s < 12; ++s) {
    const int lo = iLUT[352 - 32 * s];
    const int hi = iLUT[510 - 32 * s];
    const int ntiles = ((hi - lo + 1) + 15) >> 4;
    for (int tl = wave; tl < 2 * ntiles; tl += 8) {
      int mt = tl & 1, ntl = tl >> 1;
      bf16x8 a0 = ldfrag(smem, K_OFF, 32 * s + 16 * mt + l15, 128, 0, g);
      bf16x8 a1 = ldfrag(smem, K_OFF, 32 * s + 16 * mt + l15, 128, 1, g);
      int prow = lo + 16 * ntl + l15;
      prow = prow > 383 ? 383 : prow;
      bf16x8 b0 = ldfrag(smem, PQ_OFF, prow, 128, 0, g);
      bf16x8 b1 = ldfrag(smem, PQ_OFF, prow, 128, 1, g);
      f32x4 c = {0.f, 0.f, 0.f, 0.f};
      c = MFMA16(a0, b0, c);
      c = MFMA16(a1, b1, c);
#pragma unroll
      for (int r = 0; r < 4; ++r)
        Tl[(16 * mt + 4 * g + r) * 184 + 16 * ntl + l15] = f2bf(c[r]);
    }
    __syncthreads();
    {
      const int dbase2 = qs + l15 - 32 * s - 4 * g + 383;
#pragma unroll
      for (int tt = 0; tt < 2; ++tt) {
#pragma unroll
        for (int r = 0; r < 4; ++r) {
          int idx = iLUT[dbase2 - 16 * tt - r];
          acc[2 * s + tt][r] += bf2f(Tl[(16 * tt + 4 * g + r) * 184 + idx - lo]);
        }
      }
    }
    __syncthreads();
  }

  // ---- phase 5: QK^T accumulate (A = K rows, B = Q^T)
#pragma unroll
  for (int t = 0; t < 24; ++t) {
    bf16x8 a0 = ldfrag(smem, K_OFF, 16 * t + l15, 128, 0, g);
    bf16x8 a1 = ldfrag(smem, K_OFF, 16 * t + l15, 128, 1, g);
    acc[t] = MFMA16(a0, qf0, acc[t]);
    acc[t] = MFMA16(a1, qf1, acc[t]);
  }
  __syncthreads();  // posq region dead; about to become Vt

  // ---- phase 6: stage Vt transposed from vws [s][d] (zero halo)
  for (int idx = tid; idx < 3072; idx += 512) {
    int s = idx % 384;
    int dg = idx / 384;
    int ks = n * BSZ - BSZ + s;
    uint4 v = make_uint4(0u, 0u, 0u, 0u);
    if (ks >= 0 && ks < SEQ)
      v = *(const uint4*)(vbh + (size_t)ks * HDIM + dg * 8);
    union { uint4 q; unsigned short u[8]; } w;
    w.q = v;
#pragma unroll
    for (int j = 0; j < 8; ++j) {
      int d = dg * 8 + j;
      *(unsigned short*)(smem + VT_OFF + d * 768 + ((2 * s) ^ ((d & 7) << 4))) =
          w.u[j];
    }
  }

  // ---- phase 7: softmax (in-register; q = qs + l15 fixed per lane)
  float m = -1e30f;
#pragma unroll
  for (int t = 0; t < 24; ++t)
#pragma unroll
    for (int r = 0; r < 4; ++r) m = fmaxf(m, acc[t][r]);
  m = fmaxf(m, __shfl_xor(m, 16));
  m = fmaxf(m, __shfl_xor(m, 32));
  float sum = 0.f;
#pragma unroll
  for (int t = 0; t < 24; ++t)
#pragma unroll
    for (int r = 0; r < 4; ++r) {
      float p = exp2f((acc[t][r] - m) * 0.10411790f);  // /sqrt(192) * log2e
      acc[t][r] = p;
      sum += p;
    }
  sum += __shfl_xor(sum, 16);
  sum += __shfl_xor(sum, 32);
  float inv = 1.0f / sum;

  bf16x8 pa[12];
#pragma unroll
  for (int kt = 0; kt < 12; ++kt) {
    union { bf16x8 v; unsigned short u[8]; } w;
#pragma unroll
    for (int j = 0; j < 4; ++j) w.u[j] = f2bf(acc[2 * kt][j] * inv);
#pragma unroll
    for (int j = 0; j < 4; ++j) w.u[4 + j] = f2bf(acc[2 * kt + 1][j] * inv);
    pa[kt] = w.v;
  }
  __syncthreads();  // Vt staged

  // ---- phase 8: PV, write ctx bf16
  unsigned short* ctxg = ctx + ((size_t)b * SEQ + n * BSZ) * HID + h * HDIM;
#pragma unroll
  for (int nt = 0; nt < 4; ++nt) {
    f32x4 o = {0.f, 0.f, 0.f, 0.f};
#pragma unroll
    for (int kt = 0; kt < 12; ++kt) {
      bf16x8 bv = ldfrag(smem, VT_OFF, 16 * nt + l15, 768, kt, g);
      o = MFMA16(pa[kt], bv, o);
    }
#pragma unroll
    for (int r = 0; r < 4; ++r) {
      size_t off = (size_t)(qs + 4 * g + r) * HID + 16 * nt + l15;
      ctxg[off] = f2bf(o[r]);
    }
  }
}

// ---------------------------------------------------------------------------
// Fused out-projection + bias + residual + LayerNorm.
__global__ __launch_bounds__(512) void out_ln(
    const unsigned short* __restrict__ ctx, const unsigned short* __restrict__ WoT,
    const float* __restrict__ bo, const float* __restrict__ hidden,
    const float* __restrict__ lns, const float* __restrict__ lnb,
    float* __restrict__ out) {
  extern __shared__ char smem[];
  unsigned short* Au = (unsigned short*)(smem + OL_AU);
  unsigned short* Bu = (unsigned short*)(smem + OL_BU);
  float* red1 = (float*)(smem + OL_R1);
  float* red2 = (float*)(smem + OL_R2);
  float* muA = (float*)(smem + OL_MU);
  float* rsA = (float*)(smem + OL_RS);

  const int t = threadIdx.x;
  const int lane = t & 63;
  const int l15 = lane & 15, g = lane >> 4;
  const int w = t >> 6;
  const int m0 = blockIdx.x * 64;

  f32x4 acc[4][6];
#pragma unroll
  for (int mt = 0; mt < 4; ++mt)
#pragma unroll
    for (int nt = 0; nt < 6; ++nt) acc[mt][nt] = (f32x4){0.f, 0.f, 0.f, 0.f};

  for (int k0 = 0; k0 < HID; k0 += 32) {
    if (t < 256) {
      int r = t >> 2, c = t & 3;
      uint4 v = *(const uint4*)(ctx + (size_t)(m0 + r) * HID + k0 + c * 8);
      *(uint4*)(Au + r * 40 + c * 8) = v;
    }
#pragma unroll
    for (int i = 0; i < 6; ++i) {
      int idx = t + i * 512;
      int nrow = idx >> 2, c = idx & 3;
      uint4 v = *(const uint4*)(WoT + (size_t)nrow * HID + k0 + c * 8);
      *(uint4*)(Bu + nrow * 40 + c * 8) = v;
    }
    __syncthreads();
    bf16x8 af[4];
#pragma unroll
    for (int mt = 0; mt < 4; ++mt) af[mt] = olfrag(Au, mt * 16 + l15, g);
#pragma unroll
    for (int nt = 0; nt < 6; ++nt) {
      bf16x8 bf = olfrag(Bu, w * 96 + nt * 16 + l15, g);
#pragma unroll
      for (int mt = 0; mt < 4; ++mt)
        acc[mt][nt] = MFMA16(af[mt], bf, acc[mt][nt]);
    }
    __syncthreads();
  }

  float psum[4][4] = {};
  float psq[4][4] = {};
#pragma unroll
  for (int nt = 0; nt < 6; ++nt) {
    int gn = w * 96 + nt * 16 + l15;
    float bval = bo[gn];
#pragma unroll
    for (int mt = 0; mt < 4; ++mt) {
#pragma unroll
      for (int r = 0; r < 4; ++r) {
        int gm = m0 + mt * 16 + 4 * g + r;
        float v = acc[mt][nt][r] + bval + hidden[(size_t)gm * HID + gn];
        acc[mt][nt][r] = v;
        psum[mt][r] += v;
        psq[mt][r] += v * v;
      }
    }
  }
#pragma unroll
  for (int o = 1; o < 16; o <<= 1) {
#pragma unroll
    for (int mt = 0; mt < 4; ++mt)
#pragma unroll
      for (int r = 0; r < 4; ++r) {
        psum[mt][r] += __shfl_xor(psum[mt][r], o);
        psq[mt][r] += __shfl_xor(psq[mt][r], o);
      }
  }
  if (l15 == 0) {
#pragma unroll
    for (int mt = 0; mt < 4; ++mt)
#pragma unroll
      for (int r = 0; r < 4; ++r) {
        red1[(mt * 16 + 4 * g + r) * 8 + w] = psum[mt][r];
        red2[(mt * 16 + 4 * g + r) * 8 + w] = psq[mt][r];
      }
  }
  __syncthreads();
  if (t < 64) {
    float s = 0.f, s2 = 0.f;
#pragma unroll
    for (int i = 0; i < 8; ++i) {
      s += red1[t * 8 + i];
      s2 += red2[t * 8 + i];
    }
    float mu = s * (1.0f / 768.0f);
    float var = s2 * (1.0f / 768.0f) - mu * mu;
    muA[t] = mu;
    rsA[t] = 1.0f / sqrtf(var + 1e-7f);
  }
  __syncthreads();
#pragma unroll
  for (int nt = 0; nt < 6; ++nt) {
    int gn = w * 96 + nt * 16 + l15;
    float sc = lns[gn], bi = lnb[gn];
#pragma unroll
    for (int mt = 0; mt < 4; ++mt) {
#pragma unroll
      for (int r = 0; r < 4; ++r) {
        int lm = mt * 16 + 4 * g + r;
        float v = (acc[mt][nt][r] - muA[lm]) * rsA[lm] * sc + bi;
        out[(size_t)(m0 + lm) * HID + gn] = v;
      }
    }
  }
}

extern "C" void kernel_launch(void* const* d_in, const int* in_sizes, int n_in,
                              void* d_out, int out_size, void* d_ws,
                              size_t ws_size, hipStream_t stream) {
  (void)in_sizes; (void)n_in; (void)out_size; (void)ws_size;
  const float* hidden = (const float*)d_in[0];
  const float* relpos = (const float*)d_in[1];
  const float* Wq = (const float*)d_in[2];
  const float* bq = (const float*)d_in[3];
  const float* Wk = (const float*)d_in[4];
  const float* bk = (const float*)d_in[5];
  const float* Wv = (const float*)d_in[6];
  const float* bv = (const float*)d_in[7];
  const float* Wo = (const float*)d_in[8];
  const float* bo = (const float*)d_in[9];
  const float* lns = (const float*)d_in[10];
  const float* lnb = (const float*)d_in[11];
  float* out = (float*)d_out;

  // Workspace (ushort units), total 207,618,048 B == proven footprint:
  //   qws | kws | vws | ctx(=hbf alias) | posq | posk | Wt4 (WqkvT + WoT)
  unsigned short* ws = (unsigned short*)d_ws;
  const size_t QE = (size_t)48 * SEQ * HDIM;   // 25,165,824
  const size_t PE = (size_t)NHEADS * PBUCK * HDIM;  // 393,216
  unsigned short* qws = ws;
  unsigned short* kws = qws + QE;
  unsigned short* vws = kws + QE;
  unsigned short* ctx = vws + QE;
  unsigned short* hbf = ctx;                   // alias: dead before attn writes
  unsigned short* posq = ctx + QE;
  unsigned short* posk = posq + PE;
  unsigned short* Wt4 = posk + PE;             // 4 x 589,824
  unsigned short* WoT = Wt4 + (size_t)3 * HID * HID;

  static bool attrib_set = false;
  if (!attrib_set) {
    hipFuncSetAttribute((const void*)attn_kernel,
                        hipFuncAttributeMaxDynamicSharedMemorySize, SMEM_ATTN);
    hipFuncSetAttribute((const void*)out_ln,
                        hipFuncAttributeMaxDynamicSharedMemorySize, SMEM_OL);
    attrib_set = true;
  }

  hbf_conv<<<12288, 256, 0, stream>>>(hidden, hbf);
  conv_wt<<<dim3(12, 12, 4), 256, 0, stream>>>(Wq, Wk, Wv, Wo, Wt4);
  pos_gemm<<<dim3(8, 24), 256, 0, stream>>>(relpos, Wq, Wk, bq, bk, posq, posk);
  qkv_mfma<<<dim3(18, 256), 256, 0, stream>>>(hbf, Wt4, bq, bk, bv, qws, kws,
                                              vws);
  attn_kernel<<<3072, 512, SMEM_ATTN, stream>>>(qws, kws, vws, posq, posk, ctx);
  out_ln<<<512, 512, SMEM_OL, stream>>>(ctx, WoT, bo, hidden, lns, lnb, out);
}

// Round 11
// 741.128 us; speedup vs baseline: 3.2303x; 1.0074x over previous
//
#include <hip/hip_runtime.h>
#include <math.h>

// ---------------------------------------------------------------------------
// LocalSlidingWindow_DisentangledAttention — Round 11:
//  - attn: C2P row stride 392->396 ushorts and Tl 184->186 (bank-conflict
//    elimination in gather phases; measured 3.45e7 conflict cycles), barrier
//    B2 dropped (per-wave-private C2P strip needs only lgkmcnt).
//  - qkv_mfma: XCD-chunked blockIdx swizzle (A-panel sharers -> same L2).
//  - rest identical to R10 (hbf pre-convert, in-staging V transpose, fused
//    out_ln). Workspace = 207,618,048 B (proven).
// ---------------------------------------------------------------------------

#define NHEADS 12
#define HDIM   64
#define SEQ    8192
#define HID    768
#define BSZ    128
#define WIN    384
#define PBUCK  512

typedef __attribute__((ext_vector_type(8))) short bf16x8;
typedef __attribute__((ext_vector_type(4))) float f32x4;
#define MFMA16(a, b, c) __builtin_amdgcn_mfma_f32_16x16x32_bf16((a), (b), (c), 0, 0, 0)

// attn LDS byte map (dynamic, 156288 total)
#define C2PS    396      // C2P row stride (ushorts): 792 B = 6 words mod 32
#define TLS     186      // Tl row stride (ushorts): 372 B = 29 words mod 32
#define C2P_OFF 0        // [128][396] bf16 = 101376   (phase 1-2)
#define K_OFF   0        // [384][64]  bf16 = 49152    (phase 3+)
#define PQ_OFF  49152    // [384][64]  bf16 = 49152    (phase 3-4)
#define VT_OFF  49152    // [64][384]  bf16 = 49152    (PV phase)
#define T_OFF   101376   // [32][186]  bf16 = 11904
#define Q_OFF   113280   // [128][64]  bf16 = 16384
#define PKH_OFF 129664   // [192][64]  bf16 = 24576
#define LUT_OFF 154240   // [511] int  = 2044
#define SMEM_ATTN 156288

// out_ln LDS byte map (dynamic, 71168)
#define OL_AU 0          // [64][40] bf16 = 5120
#define OL_BU 5120       // [768][40] bf16 = 61440
#define OL_R1 66560      // [64][8] f32 = 2048
#define OL_R2 68608      // [64][8] f32 = 2048
#define OL_MU 70656      // [64] f32
#define OL_RS 70912      // [64] f32
#define SMEM_OL 71168

__device__ __forceinline__ unsigned short f2bf(float f) {
  unsigned int x = __builtin_bit_cast(unsigned int, f);
  unsigned int r = (x + 0x7FFFu + ((x >> 16) & 1u)) >> 16;
  return (unsigned short)r;
}
__device__ __forceinline__ float bf2f(unsigned short u) {
  unsigned int x = ((unsigned int)u) << 16;
  return __builtin_bit_cast(float, x);
}

// idx(rel) for rel in [-383, 127]
__device__ __forceinline__ int bucket_idx(int rel) {
  if (rel >= -128) return rel + 256;
  float a = (float)(-rel);
  float t = logf(a * (1.0f / 128.0f));
  t = t / 0.6892332813f;
  t = t * 127.0f;
  int lp = (int)(ceilf(t) + 128.0f);
  int r = 256 - lp;
  return r < 0 ? 0 : r;
}

// Fragment load from swizzled row-major bf16 LDS tile.
__device__ __forceinline__ bf16x8 ldfrag(const char* sm, int byteBase, int row,
                                         int rowBytes, int slice, int g) {
  const int swz = (row & 7) << 4;
  const char* p = sm + byteBase + row * rowBytes;
  union { bf16x8 v; uint2 u2[2]; } w;
  w.u2[0] = *(const uint2*)(p + (((slice << 6) + (g << 3)) ^ swz));
  w.u2[1] = *(const uint2*)(p + (((slice << 6) + 32 + (g << 3)) ^ swz));
  return w.v;
}

// Fragment from padded (40-ushort rows, no swizzle) LDS tile for out_ln.
__device__ __forceinline__ bf16x8 olfrag(const unsigned short* base, int row,
                                         int g) {
  const unsigned short* p = base + row * 40 + 4 * g;
  union { bf16x8 v; uint2 u2[2]; } w;
  w.u2[0] = *(const uint2*)(p);
  w.u2[1] = *(const uint2*)(p + 16);
  return w.v;
}

// ---------------------------------------------------------------------------
// hidden fp32 -> bf16 (one pass; hbf aliases ctx region, dead before attn)
__global__ __launch_bounds__(256) void hbf_conv(const float* __restrict__ src,
                                                unsigned short* __restrict__ dst) {
  size_t i = ((size_t)blockIdx.x * 256 + threadIdx.x) * 8;
  float4 a = *(const float4*)(src + i);
  float4 b = *(const float4*)(src + i + 4);
  union { uint4 q; unsigned short u[8]; } w;
  w.u[0] = f2bf(a.x); w.u[1] = f2bf(a.y); w.u[2] = f2bf(a.z); w.u[3] = f2bf(a.w);
  w.u[4] = f2bf(b.x); w.u[5] = f2bf(b.y); w.u[6] = f2bf(b.z); w.u[7] = f2bf(b.w);
  *(uint4*)(dst + i) = w.q;
}

// Weight transpose fp32 -> bf16: Wt[z*768 + n][k] = W_z[k][n], z = 0..3
__global__ __launch_bounds__(256) void conv_wt(const float* __restrict__ W0,
                                               const float* __restrict__ W1,
                                               const float* __restrict__ W2,
                                               const float* __restrict__ W3,
                                               unsigned short* __restrict__ Wt) {
  __shared__ float tile[64][65];
  int bx = blockIdx.x, by = blockIdx.y, z = blockIdx.z;
  const float* W = (z == 0) ? W0 : (z == 1 ? W1 : (z == 2 ? W2 : W3));
  int t = threadIdx.x;
  int c = t & 63, r0 = (t >> 6) * 16;
#pragma unroll
  for (int rr = 0; rr < 16; ++rr)
    tile[r0 + rr][c] = W[(size_t)(by * 64 + r0 + rr) * HID + bx * 64 + c];
  __syncthreads();
#pragma unroll
  for (int rr = 0; rr < 16; ++rr) {
    int nw = r0 + rr;
    Wt[((size_t)z * HID + bx * 64 + nw) * HID + by * 64 + c] = f2bf(tile[c][nw]);
  }
}

// Positional projection (fp32 math) -> bf16 posq/posk [h][512][64]
__global__ __launch_bounds__(256) void pos_gemm(
    const float* __restrict__ relpos, const float* __restrict__ Wq,
    const float* __restrict__ Wk, const float* __restrict__ bq,
    const float* __restrict__ bk, unsigned short* __restrict__ posq,
    unsigned short* __restrict__ posk) {
  __shared__ float At[32][68];
  __shared__ float Bs[32][68];
  int m0 = blockIdx.x * 64;
  int n0 = blockIdx.y * 64;
  int w = n0 / HID;
  int nc0 = n0 % HID;
  const float* W = (w == 0) ? Wq : Wk;
  const float* bias = (w == 0) ? bq : bk;
  int t = threadIdx.x;
  int tx = t & 15, ty = t >> 4;
  float acc[4][4] = {};
  for (int k0 = 0; k0 < HID; k0 += 32) {
#pragma unroll
    for (int u = 0; u < 2; ++u) {
      int f = t * 2 + u;
      int r = f >> 3, c4 = f & 7;
      float4 av = *(const float4*)(relpos + (size_t)(m0 + r) * HID + k0 + c4 * 4);
      At[c4 * 4 + 0][r] = av.x; At[c4 * 4 + 1][r] = av.y;
      At[c4 * 4 + 2][r] = av.z; At[c4 * 4 + 3][r] = av.w;
    }
#pragma unroll
    for (int u = 0; u < 2; ++u) {
      int f = t * 2 + u;
      int kk = f >> 4, c4 = f & 15;
      float4 bv4 = *(const float4*)(W + (size_t)(k0 + kk) * HID + nc0 + c4 * 4);
      *(float4*)&Bs[kk][c4 * 4] = bv4;
    }
    __syncthreads();
#pragma unroll
    for (int kk = 0; kk < 32; ++kk) {
      float4 a4 = *(const float4*)&At[kk][ty * 4];
      float4 b4 = *(const float4*)&Bs[kk][tx * 4];
      float av[4] = {a4.x, a4.y, a4.z, a4.w};
      float bvv[4] = {b4.x, b4.y, b4.z, b4.w};
#pragma unroll
      for (int i = 0; i < 4; ++i)
#pragma unroll
        for (int jj = 0; jj < 4; ++jj) acc[i][jj] += av[i] * bvv[jj];
    }
    __syncthreads();
  }
  int h = nc0 >> 6;
  unsigned short* dst = (w == 0) ? posq : posk;
#pragma unroll
  for (int i = 0; i < 4; ++i) {
    int p = m0 + ty * 4 + i;
    ushort4 o;
    o.x = f2bf(acc[i][0] + bias[nc0 + tx * 4 + 0]);
    o.y = f2bf(acc[i][1] + bias[nc0 + tx * 4 + 1]);
    o.z = f2bf(acc[i][2] + bias[nc0 + tx * 4 + 2]);
    o.w = f2bf(acc[i][3] + bias[nc0 + tx * 4 + 3]);
    *(ushort4*)(dst + ((size_t)h * PBUCK + p) * HDIM + tx * 4) = o;
  }
}

// ---------------------------------------------------------------------------
// QKV projection, bf16 MFMA. Tile 128x128, BK=64, 256 thr = 4 waves (2x2).
// XCD-chunked swizzle: the 18 n-tiles sharing an A-panel stay on one XCD.
__global__ __launch_bounds__(256) void qkv_mfma(
    const unsigned short* __restrict__ hbf, const unsigned short* __restrict__ Wt,
    const float* __restrict__ bq, const float* __restrict__ bk,
    const float* __restrict__ bv, unsigned short* __restrict__ qws,
    unsigned short* __restrict__ kws, unsigned short* __restrict__ vws) {
  __shared__ unsigned short As[8192];
  __shared__ unsigned short Bs[8192];
  const int t = threadIdx.x;
  const int lane = t & 63;
  const int l15 = lane & 15, g = lane >> 4;
  const int wave = t >> 6;
  const int wy = wave >> 1, wx = wave & 1;
  // 4608 blocks total; chunk of 576 per XCD (4608 % 8 == 0, bijective).
  const int bid = blockIdx.x;
  const int wg = (bid & 7) * 576 + (bid >> 3);
  const int n0 = (wg % 18) * 128;
  const int m0 = (wg / 18) * 128;

  f32x4 acc[4][4];
#pragma unroll
  for (int i = 0; i < 4; ++i)
#pragma unroll
    for (int j = 0; j < 4; ++j) acc[i][j] = (f32x4){0.f, 0.f, 0.f, 0.f};

  for (int k0 = 0; k0 < HID; k0 += 64) {
#pragma unroll
    for (int i = 0; i < 4; ++i) {
      int c = t + i * 256;
      int row = c >> 3, cx = c & 7;
      uint4 v = *(const uint4*)(hbf + (size_t)(m0 + row) * HID + k0 + cx * 8);
      *(uint4*)((char*)As + row * 128 + ((cx * 16) ^ ((row & 7) << 4))) = v;
    }
#pragma unroll
    for (int i = 0; i < 4; ++i) {
      int c = t + i * 256;
      int row = c >> 3, cx = c & 7;
      uint4 v = *(const uint4*)(Wt + (size_t)(n0 + row) * HID + k0 + cx * 8);
      *(uint4*)((char*)Bs + row * 128 + ((cx * 16) ^ ((row & 7) << 4))) = v;
    }
    __syncthreads();
    bf16x8 af[4][2], bf[4][2];
#pragma unroll
    for (int mt = 0; mt < 4; ++mt) {
      int row = wy * 64 + mt * 16 + l15;
      const char* p = (const char*)As + row * 128;
      int swz = (row & 7) << 4;
#pragma unroll
      for (int s = 0; s < 2; ++s)
        af[mt][s] = *(const bf16x8*)(p + ((s * 64 + g * 16) ^ swz));
    }
#pragma unroll
    for (int nt = 0; nt < 4; ++nt) {
      int row = wx * 64 + nt * 16 + l15;
      const char* p = (const char*)Bs + row * 128;
      int swz = (row & 7) << 4;
#pragma unroll
      for (int s = 0; s < 2; ++s)
        bf[nt][s] = *(const bf16x8*)(p + ((s * 64 + g * 16) ^ swz));
    }
#pragma unroll
    for (int mt = 0; mt < 4; ++mt)
#pragma unroll
      for (int nt = 0; nt < 4; ++nt) {
        acc[mt][nt] = MFMA16(af[mt][0], bf[nt][0], acc[mt][nt]);
        acc[mt][nt] = MFMA16(af[mt][1], bf[nt][1], acc[mt][nt]);
      }
    __syncthreads();
  }

  const int w = n0 / HID;  // 0:q 1:k 2:v
  const float* bias = (w == 0) ? bq : (w == 1 ? bk : bv);
  unsigned short* dst = (w == 0) ? qws : (w == 1 ? kws : vws);
#pragma unroll
  for (int nt = 0; nt < 4; ++nt) {
    int gn = n0 + wx * 64 + nt * 16 + l15;
    int nc = gn - w * HID;
    int h = nc >> 6, d = nc & 63;
    float bval = bias[nc];
#pragma unroll
    for (int mt = 0; mt < 4; ++mt) {
      f32x4 a = acc[mt][nt];
#pragma unroll
      for (int r = 0; r < 4; ++r) {
        int m = m0 + wy * 64 + mt * 16 + 4 * g + r;
        int bl = m >> 13, s = m & 8191;
        size_t bh = (size_t)bl * NHEADS + h;
        dst[(bh * SEQ + s) * HDIM + d] = f2bf(a[r] + bval);
      }
    }
  }
}

// ---------------------------------------------------------------------------
// MFMA attention — R4 skeleton; padded C2P/Tl strides; B2 removed.
__global__ __launch_bounds__(512, 2) void attn_kernel(
    const unsigned short* __restrict__ qws, const unsigned short* __restrict__ kws,
    const unsigned short* __restrict__ vws, const unsigned short* __restrict__ posq,
    const unsigned short* __restrict__ posk, unsigned short* __restrict__ ctx) {
  extern __shared__ char smem[];
  int* iLUT = (int*)(smem + LUT_OFF);
  unsigned short* C2P = (unsigned short*)(smem + C2P_OFF);
  unsigned short* Tl = (unsigned short*)(smem + T_OFF);

  const int tid = threadIdx.x;
  const int wave = tid >> 6;
  const int lane = tid & 63;
  const int l15 = lane & 15;
  const int g = lane >> 4;
  const int qs = wave << 4;

  const int n = blockIdx.x & 63;
  const int bh = blockIdx.x >> 6;
  const int h = bh % NHEADS;
  const int b = bh / NHEADS;

  const unsigned short* qsrc = qws + ((size_t)bh * SEQ + n * BSZ) * HDIM;
  const unsigned short* kbh = kws + (size_t)bh * SEQ * HDIM;
  const unsigned short* vbh = vws + (size_t)bh * SEQ * HDIM;
  const unsigned short* pqh = posq + (size_t)h * PBUCK * HDIM;
  const unsigned short* pkh = posk + (size_t)h * PBUCK * HDIM;

  // ---- phase 0: stage Q, posk half 0, fill LUT
  for (int idx = tid; idx < 128 * 8; idx += 512) {
    int row = idx >> 3, c = idx & 7;
    uint4 v = *(const uint4*)(qsrc + row * HDIM + c * 8);
    *(uint4*)(smem + Q_OFF + row * 128 + ((c * 16) ^ ((row & 7) << 4))) = v;
  }
  for (int idx = tid; idx < 192 * 8; idx += 512) {
    int row = idx >> 3, c = idx & 7;
    uint4 v = *(const uint4*)(pkh + row * HDIM + c * 8);
    *(uint4*)(smem + PKH_OFF + row * 128 + ((c * 16) ^ ((row & 7) << 4))) = v;
  }
  if (tid < 511) iLUT[tid] = bucket_idx(tid - 383);
  __syncthreads();

  bf16x8 qf0 = ldfrag(smem, Q_OFF, qs + l15, 128, 0, g);
  bf16x8 qf1 = ldfrag(smem, Q_OFF, qs + l15, 128, 1, g);

  // ---- phase 1: C2P_all[q][p] = Q . posk^T  (two halves of 192 p)
#pragma unroll
  for (int half = 0; half < 2; ++half) {
    if (half) {
      __syncthreads();
      for (int idx = tid; idx < 192 * 8; idx += 512) {
        int row = idx >> 3, c = idx & 7;
        uint4 v = *(const uint4*)(pkh + (192 + row) * HDIM + c * 8);
        *(uint4*)(smem + PKH_OFF + row * 128 + ((c * 16) ^ ((row & 7) << 4))) = v;
      }
      __syncthreads();
    }
    for (int ntl = 0; ntl < 12; ++ntl) {
      bf16x8 b0 = ldfrag(smem, PKH_OFF, 16 * ntl + l15, 128, 0, g);
      bf16x8 b1 = ldfrag(smem, PKH_OFF, 16 * ntl + l15, 128, 1, g);
      f32x4 c = {0.f, 0.f, 0.f, 0.f};
      c = MFMA16(qf0, b0, c);
      c = MFMA16(qf1, b1, c);
      int p = half * 192 + 16 * ntl + l15;
#pragma unroll
      for (int r = 0; r < 4; ++r)
        C2P[(qs + 4 * g + r) * C2PS + p] = f2bf(c[r]);
    }
  }
  // No barrier: each wave gathers ONLY from its own 16-row C2P strip.
  asm volatile("s_waitcnt lgkmcnt(0)" ::: "memory");

  // ---- phase 2: S accumulators init with gathered c2p
  f32x4 acc[24];
  {
    const int qrow = qs + l15;
    const unsigned short* c2pRow = C2P + qrow * C2PS;
    const int dbase = qrow - 4 * g + 383;
#pragma unroll
    for (int t = 0; t < 24; ++t) {
#pragma unroll
      for (int r = 0; r < 4; ++r) {
        int idx = iLUT[dbase - 16 * t - r];
        acc[t][r] = bf2f(c2pRow[idx]);
      }
    }
  }
  __syncthreads();  // C2P dead

  // ---- phase 3: stage K and posq (zero-fill outside [0,SEQ))
  for (int idx = tid; idx < 384 * 8; idx += 512) {
    int row = idx >> 3, c = idx & 7;
    int ks = n * BSZ - BSZ + row;
    uint4 v = make_uint4(0u, 0u, 0u, 0u);
    if (ks >= 0 && ks < SEQ) v = *(const uint4*)(kbh + (size_t)ks * HDIM + c * 8);
    *(uint4*)(smem + K_OFF + row * 128 + ((c * 16) ^ ((row & 7) << 4))) = v;
  }
  for (int idx = tid; idx < 384 * 8; idx += 512) {
    int row = idx >> 3, c = idx & 7;
    uint4 v = *(const uint4*)(pqh + row * HDIM + c * 8);
    *(uint4*)(smem + PQ_OFF + row * 128 + ((c * 16) ^ ((row & 7) << 4))) = v;
  }
  __syncthreads();

  // ---- phase 4: p2c, 12 subtiles of 32 kwin
#pragma unroll
  for (int s = 0; s < 12; ++s) {
    const int lo = iLUT[352 - 32 * s];
    const int hi = iLUT[510 - 32 * s];
    const int ntiles = ((hi - lo + 1) + 15) >> 4;
    for (int tl = wave; tl < 2 * ntiles; tl += 8) {
      int mt = tl & 1, ntl = tl >> 1;
      bf16x8 a0 = ldfrag(smem, K_OFF, 32 * s + 16 * mt + l15, 128, 0, g);
      bf16x8 a1 = ldfrag(smem, K_OFF, 32 * s + 16 * mt + l15, 128, 1, g);
      int prow = lo + 16 * ntl + l15;
      prow = prow > 383 ? 383 : prow;
      bf16x8 b0 = ldfrag(smem, PQ_OFF, prow, 128, 0, g);
      bf16x8 b1 = ldfrag(smem, PQ_OFF, prow, 128, 1, g);
      f32x4 c = {0.f, 0.f, 0.f, 0.f};
      c = MFMA16(a0, b0, c);
      c = MFMA16(a1, b1, c);
#pragma unroll
      for (int r = 0; r < 4; ++r)
        Tl[(16 * mt + 4 * g + r) * TLS + 16 * ntl + l15] = f2bf(c[r]);
    }
    __syncthreads();
    {
      const int dbase2 = qs + l15 - 32 * s - 4 * g + 383;
#pragma unroll
      for (int tt = 0; tt < 2; ++tt) {
#pragma unroll
        for (int r = 0; r < 4; ++r) {
          int idx = iLUT[dbase2 - 16 * tt - r];
          acc[2 * s + tt][r] += bf2f(Tl[(16 * tt + 4 * g + r) * TLS + idx - lo]);
        }
      }
    }
    __syncthreads();
  }

  // ---- phase 5: QK^T accumulate (A = K rows, B = Q^T)
#pragma unroll
  for (int t = 0; t < 24; ++t) {
    bf16x8 a0 = ldfrag(smem, K_OFF, 16 * t + l15, 128, 0, g);
    bf16x8 a1 = ldfrag(smem, K_OFF, 16 * t + l15, 128, 1, g);
    acc[t] = MFMA16(a0, qf0, acc[t]);
    acc[t] = MFMA16(a1, qf1, acc[t]);
  }
  __syncthreads();  // posq region dead; about to become Vt

  // ---- phase 6: stage Vt transposed from vws [s][d] (zero halo)
  for (int idx = tid; idx < 3072; idx += 512) {
    int s = idx % 384;
    int dg = idx / 384;
    int ks = n * BSZ - BSZ + s;
    uint4 v = make_uint4(0u, 0u, 0u, 0u);
    if (ks >= 0 && ks < SEQ)
      v = *(const uint4*)(vbh + (size_t)ks * HDIM + dg * 8);
    union { uint4 q; unsigned short u[8]; } w;
    w.q = v;
#pragma unroll
    for (int j = 0; j < 8; ++j) {
      int d = dg * 8 + j;
      *(unsigned short*)(smem + VT_OFF + d * 768 + ((2 * s) ^ ((d & 7) << 4))) =
          w.u[j];
    }
  }

  // ---- phase 7: softmax (in-register; q = qs + l15 fixed per lane)
  float m = -1e30f;
#pragma unroll
  for (int t = 0; t < 24; ++t)
#pragma unroll
    for (int r = 0; r < 4; ++r) m = fmaxf(m, acc[t][r]);
  m = fmaxf(m, __shfl_xor(m, 16));
  m = fmaxf(m, __shfl_xor(m, 32));
  float sum = 0.f;
#pragma unroll
  for (int t = 0; t < 24; ++t)
#pragma unroll
    for (int r = 0; r < 4; ++r) {
      float p = exp2f((acc[t][r] - m) * 0.10411790f);  // /sqrt(192) * log2e
      acc[t][r] = p;
      sum += p;
    }
  sum += __shfl_xor(sum, 16);
  sum += __shfl_xor(sum, 32);
  float inv = 1.0f / sum;

  bf16x8 pa[12];
#pragma unroll
  for (int kt = 0; kt < 12; ++kt) {
    union { bf16x8 v; unsigned short u[8]; } w;
#pragma unroll
    for (int j = 0; j < 4; ++j) w.u[j] = f2bf(acc[2 * kt][j] * inv);
#pragma unroll
    for (int j = 0; j < 4; ++j) w.u[4 + j] = f2bf(acc[2 * kt + 1][j] * inv);
    pa[kt] = w.v;
  }
  __syncthreads();  // Vt staged

  // ---- phase 8: PV, write ctx bf16
  unsigned short* ctxg = ctx + ((size_t)b * SEQ + n * BSZ) * HID + h * HDIM;
#pragma unroll
  for (int nt = 0; nt < 4; ++nt) {
    f32x4 o = {0.f, 0.f, 0.f, 0.f};
#pragma unroll
    for (int kt = 0; kt < 12; ++kt) {
      bf16x8 bv = ldfrag(smem, VT_OFF, 16 * nt + l15, 768, kt, g);
      o = MFMA16(pa[kt], bv, o);
    }
#pragma unroll
    for (int r = 0; r < 4; ++r) {
      size_t off = (size_t)(qs + 4 * g + r) * HID + 16 * nt + l15;
      ctxg[off] = f2bf(o[r]);
    }
  }
}

// ---------------------------------------------------------------------------
// Fused out-projection + bias + residual + LayerNorm.
__global__ __launch_bounds__(512) void out_ln(
    const unsigned short* __restrict__ ctx, const unsigned short* __restrict__ WoT,
    const float* __restrict__ bo, const float* __restrict__ hidden,
    const float* __restrict__ lns, const float* __restrict__ lnb,
    float* __restrict__ out) {
  extern __shared__ char smem[];
  unsigned short* Au = (unsigned short*)(smem + OL_AU);
  unsigned short* Bu = (unsigned short*)(smem + OL_BU);
  float* red1 = (float*)(smem + OL_R1);
  float* red2 = (float*)(smem + OL_R2);
  float* muA = (float*)(smem + OL_MU);
  float* rsA = (float*)(smem + OL_RS);

  const int t = threadIdx.x;
  const int lane = t & 63;
  const int l15 = lane & 15, g = lane >> 4;
  const int w = t >> 6;
  const int m0 = blockIdx.x * 64;

  f32x4 acc[4][6];
#pragma unroll
  for (int mt = 0; mt < 4; ++mt)
#pragma unroll
    for (int nt = 0; nt < 6; ++nt) acc[mt][nt] = (f32x4){0.f, 0.f, 0.f, 0.f};

  for (int k0 = 0; k0 < HID; k0 += 32) {
    if (t < 256) {
      int r = t >> 2, c = t & 3;
      uint4 v = *(const uint4*)(ctx + (size_t)(m0 + r) * HID + k0 + c * 8);
      *(uint4*)(Au + r * 40 + c * 8) = v;
    }
#pragma unroll
    for (int i = 0; i < 6; ++i) {
      int idx = t + i * 512;
      int nrow = idx >> 2, c = idx & 3;
      uint4 v = *(const uint4*)(WoT + (size_t)nrow * HID + k0 + c * 8);
      *(uint4*)(Bu + nrow * 40 + c * 8) = v;
    }
    __syncthreads();
    bf16x8 af[4];
#pragma unroll
    for (int mt = 0; mt < 4; ++mt) af[mt] = olfrag(Au, mt * 16 + l15, g);
#pragma unroll
    for (int nt = 0; nt < 6; ++nt) {
      bf16x8 bf = olfrag(Bu, w * 96 + nt * 16 + l15, g);
#pragma unroll
      for (int mt = 0; mt < 4; ++mt)
        acc[mt][nt] = MFMA16(af[mt], bf, acc[mt][nt]);
    }
    __syncthreads();
  }

  float psum[4][4] = {};
  float psq[4][4] = {};
#pragma unroll
  for (int nt = 0; nt < 6; ++nt) {
    int gn = w * 96 + nt * 16 + l15;
    float bval = bo[gn];
#pragma unroll
    for (int mt = 0; mt < 4; ++mt) {
#pragma unroll
      for (int r = 0; r < 4; ++r) {
        int gm = m0 + mt * 16 + 4 * g + r;
        float v = acc[mt][nt][r] + bval + hidden[(size_t)gm * HID + gn];
        acc[mt][nt][r] = v;
        psum[mt][r] += v;
        psq[mt][r] += v * v;
      }
    }
  }
#pragma unroll
  for (int o = 1; o < 16; o <<= 1) {
#pragma unroll
    for (int mt = 0; mt < 4; ++mt)
#pragma unroll
      for (int r = 0; r < 4; ++r) {
        psum[mt][r] += __shfl_xor(psum[mt][r], o);
        psq[mt][r] += __shfl_xor(psq[mt][r], o);
      }
  }
  if (l15 == 0) {
#pragma unroll
    for (int mt = 0; mt < 4; ++mt)
#pragma unroll
      for (int r = 0; r < 4; ++r) {
        red1[(mt * 16 + 4 * g + r) * 8 + w] = psum[mt][r];
        red2[(mt * 16 + 4 * g + r) * 8 + w] = psq[mt][r];
      }
  }
  __syncthreads();
  if (t < 64) {
    float s = 0.f, s2 = 0.f;
#pragma unroll
    for (int i = 0; i < 8; ++i) {
      s += red1[t * 8 + i];
      s2 += red2[t * 8 + i];
    }
    float mu = s * (1.0f / 768.0f);
    float var = s2 * (1.0f / 768.0f) - mu * mu;
    muA[t] = mu;
    rsA[t] = 1.0f / sqrtf(var + 1e-7f);
  }
  __syncthreads();
#pragma unroll
  for (int nt = 0; nt < 6; ++nt) {
    int gn = w * 96 + nt * 16 + l15;
    float sc = lns[gn], bi = lnb[gn];
#pragma unroll
    for (int mt = 0; mt < 4; ++mt) {
#pragma unroll
      for (int r = 0; r < 4; ++r) {
        int lm = mt * 16 + 4 * g + r;
        float v = (acc[mt][nt][r] - muA[lm]) * rsA[lm] * sc + bi;
        out[(size_t)(m0 + lm) * HID + gn] = v;
      }
    }
  }
}

extern "C" void kernel_launch(void* const* d_in, const int* in_sizes, int n_in,
                              void* d_out, int out_size, void* d_ws,
                              size_t ws_size, hipStream_t stream) {
  (void)in_sizes; (void)n_in; (void)out_size; (void)ws_size;
  const float* hidden = (const float*)d_in[0];
  const float* relpos = (const float*)d_in[1];
  const float* Wq = (const float*)d_in[2];
  const float* bq = (const float*)d_in[3];
  const float* Wk = (const float*)d_in[4];
  const float* bk = (const float*)d_in[5];
  const float* Wv = (const float*)d_in[6];
  const float* bv = (const float*)d_in[7];
  const float* Wo = (const float*)d_in[8];
  const float* bo = (const float*)d_in[9];
  const float* lns = (const float*)d_in[10];
  const float* lnb = (const float*)d_in[11];
  float* out = (float*)d_out;

  // Workspace (ushort units), total 207,618,048 B == proven footprint:
  //   qws | kws | vws | ctx(=hbf alias) | posq | posk | Wt4 (WqkvT + WoT)
  unsigned short* ws = (unsigned short*)d_ws;
  const size_t QE = (size_t)48 * SEQ * HDIM;   // 25,165,824
  const size_t PE = (size_t)NHEADS * PBUCK * HDIM;  // 393,216
  unsigned short* qws = ws;
  unsigned short* kws = qws + QE;
  unsigned short* vws = kws + QE;
  unsigned short* ctx = vws + QE;
  unsigned short* hbf = ctx;                   // alias: dead before attn writes
  unsigned short* posq = ctx + QE;
  unsigned short* posk = posq + PE;
  unsigned short* Wt4 = posk + PE;             // 4 x 589,824
  unsigned short* WoT = Wt4 + (size_t)3 * HID * HID;

  static bool attrib_set = false;
  if (!attrib_set) {
    hipFuncSetAttribute((const void*)attn_kernel,
                        hipFuncAttributeMaxDynamicSharedMemorySize, SMEM_ATTN);
    hipFuncSetAttribute((const void*)out_ln,
                        hipFuncAttributeMaxDynamicSharedMemorySize, SMEM_OL);
    attrib_set = true;
  }

  hbf_conv<<<12288, 256, 0, stream>>>(hidden, hbf);
  conv_wt<<<dim3(12, 12, 4), 256, 0, stream>>>(Wq, Wk, Wv, Wo, Wt4);
  pos_gemm<<<dim3(8, 24), 256, 0, stream>>>(relpos, Wq, Wk, bq, bk, posq, posk);
  qkv_mfma<<<4608, 256, 0, stream>>>(hbf, Wt4, bq, bk, bv, qws, kws, vws);
  attn_kernel<<<3072, 512, SMEM_ATTN, stream>>>(qws, kws, vws, posq, posk, ctx);
  out_ln<<<512, 512, SMEM_OL, stream>>>(ctx, WoT, bo, hidden, lns, lnb, out);
}

// Round 12
// 686.515 us; speedup vs baseline: 3.4873x; 1.0796x over previous
//
#include <hip/hip_runtime.h>
#include <math.h>

// ---------------------------------------------------------------------------
// LocalSlidingWindow_DisentangledAttention — Round 12:
//  - attn: fragment-major LDS layout — each MFMA fragment is ONE contiguous
//    ds_read_b128 (was 2x ds_read_b64 with 4-way aliasing; conflict counter
//    was invariant under stride padding -> conflicts live in fragment reads).
//  - qkv_mfma: global_load_lds width-16 staging (linear LDS dest, per-lane
//    pre-swizzled global source), removes VGPR round-trip.
//  - rest identical to R11. Workspace = 207,618,048 B (proven).
// ---------------------------------------------------------------------------

#define NHEADS 12
#define HDIM   64
#define SEQ    8192
#define HID    768
#define BSZ    128
#define WIN    384
#define PBUCK  512

typedef __attribute__((ext_vector_type(8))) short bf16x8;
typedef __attribute__((ext_vector_type(4))) float f32x4;
#define MFMA16(a, b, c) __builtin_amdgcn_mfma_f32_16x16x32_bf16((a), (b), (c), 0, 0, 0)

// attn LDS byte map (dynamic, 156288 total)
#define C2PS    396      // C2P row stride (ushorts)
#define TLS     186      // Tl row stride (ushorts)
#define C2P_OFF 0        // [128][396] bf16 = 101376   (phase 1-2)
#define K_OFF   0        // [384][64]  bf16 = 49152    (phase 3+)
#define PQ_OFF  49152    // [384][64]  bf16 = 49152    (phase 3-4)
#define VT_OFF  49152    // [64][384]  bf16 = 49152    (PV phase)
#define T_OFF   101376   // [32][186]  bf16 = 11904
#define Q_OFF   113280   // [128][64]  bf16 = 16384
#define PKH_OFF 129664   // [192][64]  bf16 = 24576
#define LUT_OFF 154240   // [511] int  = 2044
#define SMEM_ATTN 156288

// out_ln LDS byte map (dynamic, 71168)
#define OL_AU 0          // [64][40] bf16 = 5120
#define OL_BU 5120       // [768][40] bf16 = 61440
#define OL_R1 66560      // [64][8] f32 = 2048
#define OL_R2 68608      // [64][8] f32 = 2048
#define OL_MU 70656      // [64] f32
#define OL_RS 70912      // [64] f32
#define SMEM_OL 71168

typedef __attribute__((address_space(3))) unsigned int lds_uint;
typedef const __attribute__((address_space(1))) unsigned int glob_uint;

__device__ __forceinline__ unsigned short f2bf(float f) {
  unsigned int x = __builtin_bit_cast(unsigned int, f);
  unsigned int r = (x + 0x7FFFu + ((x >> 16) & 1u)) >> 16;
  return (unsigned short)r;
}
__device__ __forceinline__ float bf2f(unsigned short u) {
  unsigned int x = ((unsigned int)u) << 16;
  return __builtin_bit_cast(float, x);
}

// idx(rel) for rel in [-383, 127]
__device__ __forceinline__ int bucket_idx(int rel) {
  if (rel >= -128) return rel + 256;
  float a = (float)(-rel);
  float t = logf(a * (1.0f / 128.0f));
  t = t / 0.6892332813f;
  t = t * 127.0f;
  int lp = (int)(ceilf(t) + 128.0f);
  int r = 256 - lp;
  return r < 0 ? 0 : r;
}

// ---- fragment-major layout helpers (attn) ----
// Row of 64 bf16: old elem o = s*32 + h*16 + g*4 + e  ->  new = s*32+g*8+h*4+e.
// Fragment (s,g) = 16 contiguous bytes at (s*64 + g*16) ^ ((row&7)<<4).
__device__ __forceinline__ bf16x8 ldfrag128(const char* sm, int byteBase,
                                            int row, int rowBytes, int slice,
                                            int g) {
  const int swz = (row & 7) << 4;
  return *(const bf16x8*)(sm + byteBase + row * rowBytes +
                          (((slice << 6) + (g << 4)) ^ swz));
}
// Store old-layout chunk c (elems 8c..8c+7 as uint4) into fragment-major row.
__device__ __forceinline__ void stfrag(char* base, int row, int rowBytes,
                                       int c, uint4 v) {
  const int swz = (row & 7) << 4;
  const int s = c >> 2, h = (c >> 1) & 1;
  const int n1 = s * 64 + ((2 * c) & 3) * 16 + h * 8;
  const int n2 = s * 64 + ((2 * c + 1) & 3) * 16 + h * 8;
  char* p = base + row * rowBytes;
  *(uint2*)(p + (n1 ^ swz)) = make_uint2(v.x, v.y);
  *(uint2*)(p + (n2 ^ swz)) = make_uint2(v.z, v.w);
}
// new column index for a single old column o (VT scalar staging)
__device__ __forceinline__ int vperm(int o) {
  return (o & ~31) + (((o >> 2) & 3) << 3) + (((o >> 4) & 1) << 2) + (o & 3);
}

// old-layout fragment read (qkv/out_ln keep the old 2x8B pattern)
__device__ __forceinline__ bf16x8 ldfrag(const char* sm, int byteBase, int row,
                                         int rowBytes, int slice, int g) {
  const int swz = (row & 7) << 4;
  const char* p = sm + byteBase + row * rowBytes;
  union { bf16x8 v; uint2 u2[2]; } w;
  w.u2[0] = *(const uint2*)(p + (((slice << 6) + (g << 3)) ^ swz));
  w.u2[1] = *(const uint2*)(p + (((slice << 6) + 32 + (g << 3)) ^ swz));
  return w.v;
}

// Fragment from padded (40-ushort rows, no swizzle) LDS tile for out_ln.
__device__ __forceinline__ bf16x8 olfrag(const unsigned short* base, int row,
                                         int g) {
  const unsigned short* p = base + row * 40 + 4 * g;
  union { bf16x8 v; uint2 u2[2]; } w;
  w.u2[0] = *(const uint2*)(p);
  w.u2[1] = *(const uint2*)(p + 16);
  return w.v;
}

// ---------------------------------------------------------------------------
// hidden fp32 -> bf16
__global__ __launch_bounds__(256) void hbf_conv(const float* __restrict__ src,
                                                unsigned short* __restrict__ dst) {
  size_t i = ((size_t)blockIdx.x * 256 + threadIdx.x) * 8;
  float4 a = *(const float4*)(src + i);
  float4 b = *(const float4*)(src + i + 4);
  union { uint4 q; unsigned short u[8]; } w;
  w.u[0] = f2bf(a.x); w.u[1] = f2bf(a.y); w.u[2] = f2bf(a.z); w.u[3] = f2bf(a.w);
  w.u[4] = f2bf(b.x); w.u[5] = f2bf(b.y); w.u[6] = f2bf(b.z); w.u[7] = f2bf(b.w);
  *(uint4*)(dst + i) = w.q;
}

// Weight transpose fp32 -> bf16: Wt[z*768 + n][k] = W_z[k][n], z = 0..3
__global__ __launch_bounds__(256) void conv_wt(const float* __restrict__ W0,
                                               const float* __restrict__ W1,
                                               const float* __restrict__ W2,
                                               const float* __restrict__ W3,
                                               unsigned short* __restrict__ Wt) {
  __shared__ float tile[64][65];
  int bx = blockIdx.x, by = blockIdx.y, z = blockIdx.z;
  const float* W = (z == 0) ? W0 : (z == 1 ? W1 : (z == 2 ? W2 : W3));
  int t = threadIdx.x;
  int c = t & 63, r0 = (t >> 6) * 16;
#pragma unroll
  for (int rr = 0; rr < 16; ++rr)
    tile[r0 + rr][c] = W[(size_t)(by * 64 + r0 + rr) * HID + bx * 64 + c];
  __syncthreads();
#pragma unroll
  for (int rr = 0; rr < 16; ++rr) {
    int nw = r0 + rr;
    Wt[((size_t)z * HID + bx * 64 + nw) * HID + by * 64 + c] = f2bf(tile[c][nw]);
  }
}

// Positional projection (fp32 math) -> bf16 posq/posk [h][512][64]
__global__ __launch_bounds__(256) void pos_gemm(
    const float* __restrict__ relpos, const float* __restrict__ Wq,
    const float* __restrict__ Wk, const float* __restrict__ bq,
    const float* __restrict__ bk, unsigned short* __restrict__ posq,
    unsigned short* __restrict__ posk) {
  __shared__ float At[32][68];
  __shared__ float Bs[32][68];
  int m0 = blockIdx.x * 64;
  int n0 = blockIdx.y * 64;
  int w = n0 / HID;
  int nc0 = n0 % HID;
  const float* W = (w == 0) ? Wq : Wk;
  const float* bias = (w == 0) ? bq : bk;
  int t = threadIdx.x;
  int tx = t & 15, ty = t >> 4;
  float acc[4][4] = {};
  for (int k0 = 0; k0 < HID; k0 += 32) {
#pragma unroll
    for (int u = 0; u < 2; ++u) {
      int f = t * 2 + u;
      int r = f >> 3, c4 = f & 7;
      float4 av = *(const float4*)(relpos + (size_t)(m0 + r) * HID + k0 + c4 * 4);
      At[c4 * 4 + 0][r] = av.x; At[c4 * 4 + 1][r] = av.y;
      At[c4 * 4 + 2][r] = av.z; At[c4 * 4 + 3][r] = av.w;
    }
#pragma unroll
    for (int u = 0; u < 2; ++u) {
      int f = t * 2 + u;
      int kk = f >> 4, c4 = f & 15;
      float4 bv4 = *(const float4*)(W + (size_t)(k0 + kk) * HID + nc0 + c4 * 4);
      *(float4*)&Bs[kk][c4 * 4] = bv4;
    }
    __syncthreads();
#pragma unroll
    for (int kk = 0; kk < 32; ++kk) {
      float4 a4 = *(const float4*)&At[kk][ty * 4];
      float4 b4 = *(const float4*)&Bs[kk][tx * 4];
      float av[4] = {a4.x, a4.y, a4.z, a4.w};
      float bvv[4] = {b4.x, b4.y, b4.z, b4.w};
#pragma unroll
      for (int i = 0; i < 4; ++i)
#pragma unroll
        for (int jj = 0; jj < 4; ++jj) acc[i][jj] += av[i] * bvv[jj];
    }
    __syncthreads();
  }
  int h = nc0 >> 6;
  unsigned short* dst = (w == 0) ? posq : posk;
#pragma unroll
  for (int i = 0; i < 4; ++i) {
    int p = m0 + ty * 4 + i;
    ushort4 o;
    o.x = f2bf(acc[i][0] + bias[nc0 + tx * 4 + 0]);
    o.y = f2bf(acc[i][1] + bias[nc0 + tx * 4 + 1]);
    o.z = f2bf(acc[i][2] + bias[nc0 + tx * 4 + 2]);
    o.w = f2bf(acc[i][3] + bias[nc0 + tx * 4 + 3]);
    *(ushort4*)(dst + ((size_t)h * PBUCK + p) * HDIM + tx * 4) = o;
  }
}

// ---------------------------------------------------------------------------
// QKV projection, bf16 MFMA. Tile 128x128, BK=64, 256 thr = 4 waves (2x2).
// Staging via global_load_lds width-16: linear LDS dest, source col chunk
// cx = slot ^ (row&7) reproduces the XOR-swizzled layout for old ldfrag.
__global__ __launch_bounds__(256) void qkv_mfma(
    const unsigned short* __restrict__ hbf, const unsigned short* __restrict__ Wt,
    const float* __restrict__ bq, const float* __restrict__ bk,
    const float* __restrict__ bv, unsigned short* __restrict__ qws,
    unsigned short* __restrict__ kws, unsigned short* __restrict__ vws) {
  __shared__ unsigned short As[8192];
  __shared__ unsigned short Bs[8192];
  const int t = threadIdx.x;
  const int lane = t & 63;
  const int l15 = lane & 15, g = lane >> 4;
  const int wave = t >> 6;
  const int wy = wave >> 1, wx = wave & 1;
  const int bid = blockIdx.x;
  const int wg = (bid & 7) * 576 + (bid >> 3);
  const int n0 = (wg % 18) * 128;
  const int m0 = (wg / 18) * 128;

  // per-lane source row/col for the 4 glds calls (1 KB each per wave)
  const int rsub = lane >> 3;          // 0..7 within the 8-row chunk
  const int slot = lane & 7;

  f32x4 acc[4][4];
#pragma unroll
  for (int i = 0; i < 4; ++i)
#pragma unroll
    for (int j = 0; j < 4; ++j) acc[i][j] = (f32x4){0.f, 0.f, 0.f, 0.f};

  for (int k0 = 0; k0 < HID; k0 += 64) {
#pragma unroll
    for (int i = 0; i < 4; ++i) {
      int row = wave * 32 + i * 8 + rsub;
      int cx = slot ^ (row & 7);
      const unsigned short* src = hbf + (size_t)(m0 + row) * HID + k0 + cx * 8;
      __builtin_amdgcn_global_load_lds(
          (glob_uint*)src, (lds_uint*)((char*)As + wave * 4096 + i * 1024),
          16, 0, 0);
    }
#pragma unroll
    for (int i = 0; i < 4; ++i) {
      int row = wave * 32 + i * 8 + rsub;
      int cx = slot ^ (row & 7);
      const unsigned short* src = Wt + (size_t)(n0 + row) * HID + k0 + cx * 8;
      __builtin_amdgcn_global_load_lds(
          (glob_uint*)src, (lds_uint*)((char*)Bs + wave * 4096 + i * 1024),
          16, 0, 0);
    }
    __syncthreads();
    bf16x8 af[4][2], bf[4][2];
#pragma unroll
    for (int mt = 0; mt < 4; ++mt) {
      int row = wy * 64 + mt * 16 + l15;
#pragma unroll
      for (int s = 0; s < 2; ++s)
        af[mt][s] = ldfrag((const char*)As, 0, row, 128, s, g);
    }
#pragma unroll
    for (int nt = 0; nt < 4; ++nt) {
      int row = wx * 64 + nt * 16 + l15;
#pragma unroll
      for (int s = 0; s < 2; ++s)
        bf[nt][s] = ldfrag((const char*)Bs, 0, row, 128, s, g);
    }
#pragma unroll
    for (int mt = 0; mt < 4; ++mt)
#pragma unroll
      for (int nt = 0; nt < 4; ++nt) {
        acc[mt][nt] = MFMA16(af[mt][0], bf[nt][0], acc[mt][nt]);
        acc[mt][nt] = MFMA16(af[mt][1], bf[nt][1], acc[mt][nt]);
      }
    __syncthreads();
  }

  const int w = n0 / HID;  // 0:q 1:k 2:v
  const float* bias = (w == 0) ? bq : (w == 1 ? bk : bv);
  unsigned short* dst = (w == 0) ? qws : (w == 1 ? kws : vws);
#pragma unroll
  for (int nt = 0; nt < 4; ++nt) {
    int gn = n0 + wx * 64 + nt * 16 + l15;
    int nc = gn - w * HID;
    int h = nc >> 6, d = nc & 63;
    float bval = bias[nc];
#pragma unroll
    for (int mt = 0; mt < 4; ++mt) {
      f32x4 a = acc[mt][nt];
#pragma unroll
      for (int r = 0; r < 4; ++r) {
        int m = m0 + wy * 64 + mt * 16 + 4 * g + r;
        int bl = m >> 13, s = m & 8191;
        size_t bh = (size_t)bl * NHEADS + h;
        dst[(bh * SEQ + s) * HDIM + d] = f2bf(a[r] + bval);
      }
    }
  }
}

// ---------------------------------------------------------------------------
// MFMA attention — R4 skeleton, fragment-major LDS tiles (1x ds_read_b128).
__global__ __launch_bounds__(512, 2) void attn_kernel(
    const unsigned short* __restrict__ qws, const unsigned short* __restrict__ kws,
    const unsigned short* __restrict__ vws, const unsigned short* __restrict__ posq,
    const unsigned short* __restrict__ posk, unsigned short* __restrict__ ctx) {
  extern __shared__ char smem[];
  int* iLUT = (int*)(smem + LUT_OFF);
  unsigned short* C2P = (unsigned short*)(smem + C2P_OFF);
  unsigned short* Tl = (unsigned short*)(smem + T_OFF);

  const int tid = threadIdx.x;
  const int wave = tid >> 6;
  const int lane = tid & 63;
  const int l15 = lane & 15;
  const int g = lane >> 4;
  const int qs = wave << 4;

  const int n = blockIdx.x & 63;
  const int bh = blockIdx.x >> 6;
  const int h = bh % NHEADS;
  const int b = bh / NHEADS;

  const unsigned short* qsrc = qws + ((size_t)bh * SEQ + n * BSZ) * HDIM;
  const unsigned short* kbh = kws + (size_t)bh * SEQ * HDIM;
  const unsigned short* vbh = vws + (size_t)bh * SEQ * HDIM;
  const unsigned short* pqh = posq + (size_t)h * PBUCK * HDIM;
  const unsigned short* pkh = posk + (size_t)h * PBUCK * HDIM;

  // ---- phase 0: stage Q, posk half 0, fill LUT (fragment-major)
  for (int idx = tid; idx < 128 * 8; idx += 512) {
    int row = idx >> 3, c = idx & 7;
    uint4 v = *(const uint4*)(qsrc + row * HDIM + c * 8);
    stfrag(smem + Q_OFF, row, 128, c, v);
  }
  for (int idx = tid; idx < 192 * 8; idx += 512) {
    int row = idx >> 3, c = idx & 7;
    uint4 v = *(const uint4*)(pkh + row * HDIM + c * 8);
    stfrag(smem + PKH_OFF, row, 128, c, v);
  }
  if (tid < 511) iLUT[tid] = bucket_idx(tid - 383);
  __syncthreads();

  bf16x8 qf0 = ldfrag128(smem, Q_OFF, qs + l15, 128, 0, g);
  bf16x8 qf1 = ldfrag128(smem, Q_OFF, qs + l15, 128, 1, g);

  // ---- phase 1: C2P_all[q][p] = Q . posk^T  (two halves of 192 p)
#pragma unroll
  for (int half = 0; half < 2; ++half) {
    if (half) {
      __syncthreads();
      for (int idx = tid; idx < 192 * 8; idx += 512) {
        int row = idx >> 3, c = idx & 7;
        uint4 v = *(const uint4*)(pkh + (192 + row) * HDIM + c * 8);
        stfrag(smem + PKH_OFF, row, 128, c, v);
      }
      __syncthreads();
    }
    for (int ntl = 0; ntl < 12; ++ntl) {
      bf16x8 b0 = ldfrag128(smem, PKH_OFF, 16 * ntl + l15, 128, 0, g);
      bf16x8 b1 = ldfrag128(smem, PKH_OFF, 16 * ntl + l15, 128, 1, g);
      f32x4 c = {0.f, 0.f, 0.f, 0.f};
      c = MFMA16(qf0, b0, c);
      c = MFMA16(qf1, b1, c);
      int p = half * 192 + 16 * ntl + l15;
#pragma unroll
      for (int r = 0; r < 4; ++r)
        C2P[(qs + 4 * g + r) * C2PS + p] = f2bf(c[r]);
    }
  }
  // No barrier: each wave gathers ONLY from its own 16-row C2P strip.
  asm volatile("s_waitcnt lgkmcnt(0)" ::: "memory");
  __builtin_amdgcn_sched_barrier(0);

  // ---- phase 2: S accumulators init with gathered c2p
  f32x4 acc[24];
  {
    const int qrow = qs + l15;
    const unsigned short* c2pRow = C2P + qrow * C2PS;
    const int dbase = qrow - 4 * g + 383;
#pragma unroll
    for (int t = 0; t < 24; ++t) {
#pragma unroll
      for (int r = 0; r < 4; ++r) {
        int idx = iLUT[dbase - 16 * t - r];
        acc[t][r] = bf2f(c2pRow[idx]);
      }
    }
  }
  __syncthreads();  // C2P dead

  // ---- phase 3: stage K and posq (zero-fill outside [0,SEQ))
  for (int idx = tid; idx < 384 * 8; idx += 512) {
    int row = idx >> 3, c = idx & 7;
    int ks = n * BSZ - BSZ + row;
    uint4 v = make_uint4(0u, 0u, 0u, 0u);
    if (ks >= 0 && ks < SEQ) v = *(const uint4*)(kbh + (size_t)ks * HDIM + c * 8);
    stfrag(smem + K_OFF, row, 128, c, v);
  }
  for (int idx = tid; idx < 384 * 8; idx += 512) {
    int row = idx >> 3, c = idx & 7;
    uint4 v = *(const uint4*)(pqh + row * HDIM + c * 8);
    stfrag(smem + PQ_OFF, row, 128, c, v);
  }
  __syncthreads();

  // ---- phase 4: p2c, 12 subtiles of 32 kwin
#pragma unroll
  for (int s = 0; s < 12; ++s) {
    const int lo = iLUT[352 - 32 * s];
    const int hi = iLUT[510 - 32 * s];
    const int ntiles = ((hi - lo + 1) + 15) >> 4;
    for (int tl = wave; tl < 2 * ntiles; tl += 8) {
      int mt = tl & 1, ntl = tl >> 1;
      bf16x8 a0 = ldfrag128(smem, K_OFF, 32 * s + 16 * mt + l15, 128, 0, g);
      bf16x8 a1 = ldfrag128(smem, K_OFF, 32 * s + 16 * mt + l15, 128, 1, g);
      int prow = lo + 16 * ntl + l15;
      prow = prow > 383 ? 383 : prow;
      bf16x8 b0 = ldfrag128(smem, PQ_OFF, prow, 128, 0, g);
      bf16x8 b1 = ldfrag128(smem, PQ_OFF, prow, 128, 1, g);
      f32x4 c = {0.f, 0.f, 0.f, 0.f};
      c = MFMA16(a0, b0, c);
      c = MFMA16(a1, b1, c);
#pragma unroll
      for (int r = 0; r < 4; ++r)
        Tl[(16 * mt + 4 * g + r) * TLS + 16 * ntl + l15] = f2bf(c[r]);
    }
    __syncthreads();
    {
      const int dbase2 = qs + l15 - 32 * s - 4 * g + 383;
#pragma unroll
      for (int tt = 0; tt < 2; ++tt) {
#pragma unroll
        for (int r = 0; r < 4; ++r) {
          int idx = iLUT[dbase2 - 16 * tt - r];
          acc[2 * s + tt][r] += bf2f(Tl[(16 * tt + 4 * g + r) * TLS + idx - lo]);
        }
      }
    }
    __syncthreads();
  }

  // ---- phase 5: QK^T accumulate (A = K rows, B = Q^T)
#pragma unroll
  for (int t = 0; t < 24; ++t) {
    bf16x8 a0 = ldfrag128(smem, K_OFF, 16 * t + l15, 128, 0, g);
    bf16x8 a1 = ldfrag128(smem, K_OFF, 16 * t + l15, 128, 1, g);
    acc[t] = MFMA16(a0, qf0, acc[t]);
    acc[t] = MFMA16(a1, qf1, acc[t]);
  }
  __syncthreads();  // posq region dead; about to become Vt

  // ---- phase 6: stage Vt transposed from vws [s][d], fragment-major cols
  for (int idx = tid; idx < 3072; idx += 512) {
    int s = idx % 384;
    int dg = idx / 384;
    int ks = n * BSZ - BSZ + s;
    uint4 v = make_uint4(0u, 0u, 0u, 0u);
    if (ks >= 0 && ks < SEQ)
      v = *(const uint4*)(vbh + (size_t)ks * HDIM + dg * 8);
    union { uint4 q; unsigned short u[8]; } w;
    w.q = v;
    const int nc = 2 * vperm(s);
#pragma unroll
    for (int j = 0; j < 8; ++j) {
      int d = dg * 8 + j;
      *(unsigned short*)(smem + VT_OFF + d * 768 + (nc ^ ((d & 7) << 4))) =
          w.u[j];
    }
  }

  // ---- phase 7: softmax (in-register; q = qs + l15 fixed per lane)
  float m = -1e30f;
#pragma unroll
  for (int t = 0; t < 24; ++t)
#pragma unroll
    for (int r = 0; r < 4; ++r) m = fmaxf(m, acc[t][r]);
  m = fmaxf(m, __shfl_xor(m, 16));
  m = fmaxf(m, __shfl_xor(m, 32));
  float sum = 0.f;
#pragma unroll
  for (int t = 0; t < 24; ++t)
#pragma unroll
    for (int r = 0; r < 4; ++r) {
      float p = exp2f((acc[t][r] - m) * 0.10411790f);  // /sqrt(192) * log2e
      acc[t][r] = p;
      sum += p;
    }
  sum += __shfl_xor(sum, 16);
  sum += __shfl_xor(sum, 32);
  float inv = 1.0f / sum;

  bf16x8 pa[12];
#pragma unroll
  for (int kt = 0; kt < 12; ++kt) {
    union { bf16x8 v; unsigned short u[8]; } w;
#pragma unroll
    for (int j = 0; j < 4; ++j) w.u[j] = f2bf(acc[2 * kt][j] * inv);
#pragma unroll
    for (int j = 0; j < 4; ++j) w.u[4 + j] = f2bf(acc[2 * kt + 1][j] * inv);
    pa[kt] = w.v;
  }
  __syncthreads();  // Vt staged

  // ---- phase 8: PV, write ctx bf16
  unsigned short* ctxg = ctx + ((size_t)b * SEQ + n * BSZ) * HID + h * HDIM;
#pragma unroll
  for (int nt = 0; nt < 4; ++nt) {
    f32x4 o = {0.f, 0.f, 0.f, 0.f};
#pragma unroll
    for (int kt = 0; kt < 12; ++kt) {
      bf16x8 bv = ldfrag128(smem, VT_OFF, 16 * nt + l15, 768, kt, g);
      o = MFMA16(pa[kt], bv, o);
    }
#pragma unroll
    for (int r = 0; r < 4; ++r) {
      size_t off = (size_t)(qs + 4 * g + r) * HID + 16 * nt + l15;
      ctxg[off] = f2bf(o[r]);
    }
  }
}

// ---------------------------------------------------------------------------
// Fused out-projection + bias + residual + LayerNorm.
__global__ __launch_bounds__(512) void out_ln(
    const unsigned short* __restrict__ ctx, const unsigned short* __restrict__ WoT,
    const float* __restrict__ bo, const float* __restrict__ hidden,
    const float* __restrict__ lns, const float* __restrict__ lnb,
    float* __restrict__ out) {
  extern __shared__ char smem[];
  unsigned short* Au = (unsigned short*)(smem + OL_AU);
  unsigned short* Bu = (unsigned short*)(smem + OL_BU);
  float* red1 = (float*)(smem + OL_R1);
  float* red2 = (float*)(smem + OL_R2);
  float* muA = (float*)(smem + OL_MU);
  float* rsA = (float*)(smem + OL_RS);

  const int t = threadIdx.x;
  const int lane = t & 63;
  const int l15 = lane & 15, g = lane >> 4;
  const int w = t >> 6;
  const int m0 = blockIdx.x * 64;

  f32x4 acc[4][6];
#pragma unroll
  for (int mt = 0; mt < 4; ++mt)
#pragma unroll
    for (int nt = 0; nt < 6; ++nt) acc[mt][nt] = (f32x4){0.f, 0.f, 0.f, 0.f};

  for (int k0 = 0; k0 < HID; k0 += 32) {
    if (t < 256) {
      int r = t >> 2, c = t & 3;
      uint4 v = *(const uint4*)(ctx + (size_t)(m0 + r) * HID + k0 + c * 8);
      *(uint4*)(Au + r * 40 + c * 8) = v;
    }
#pragma unroll
    for (int i = 0; i < 6; ++i) {
      int idx = t + i * 512;
      int nrow = idx >> 2, c = idx & 3;
      uint4 v = *(const uint4*)(WoT + (size_t)nrow * HID + k0 + c * 8);
      *(uint4*)(Bu + nrow * 40 + c * 8) = v;
    }
    __syncthreads();
    bf16x8 af[4];
#pragma unroll
    for (int mt = 0; mt < 4; ++mt) af[mt] = olfrag(Au, mt * 16 + l15, g);
#pragma unroll
    for (int nt = 0; nt < 6; ++nt) {
      bf16x8 bf = olfrag(Bu, w * 96 + nt * 16 + l15, g);
#pragma unroll
      for (int mt = 0; mt < 4; ++mt)
        acc[mt][nt] = MFMA16(af[mt], bf, acc[mt][nt]);
    }
    __syncthreads();
  }

  float psum[4][4] = {};
  float psq[4][4] = {};
#pragma unroll
  for (int nt = 0; nt < 6; ++nt) {
    int gn = w * 96 + nt * 16 + l15;
    float bval = bo[gn];
#pragma unroll
    for (int mt = 0; mt < 4; ++mt) {
#pragma unroll
      for (int r = 0; r < 4; ++r) {
        int gm = m0 + mt * 16 + 4 * g + r;
        float v = acc[mt][nt][r] + bval + hidden[(size_t)gm * HID + gn];
        acc[mt][nt][r] = v;
        psum[mt][r] += v;
        psq[mt][r] += v * v;
      }
    }
  }
#pragma unroll
  for (int o = 1; o < 16; o <<= 1) {
#pragma unroll
    for (int mt = 0; mt < 4; ++mt)
#pragma unroll
      for (int r = 0; r < 4; ++r) {
        psum[mt][r] += __shfl_xor(psum[mt][r], o);
        psq[mt][r] += __shfl_xor(psq[mt][r], o);
      }
  }
  if (l15 == 0) {
#pragma unroll
    for (int mt = 0; mt < 4; ++mt)
#pragma unroll
      for (int r = 0; r < 4; ++r) {
        red1[(mt * 16 + 4 * g + r) * 8 + w] = psum[mt][r];
        red2[(mt * 16 + 4 * g + r) * 8 + w] = psq[mt][r];
      }
  }
  __syncthreads();
  if (t < 64) {
    float s = 0.f, s2 = 0.f;
#pragma unroll
    for (int i = 0; i < 8; ++i) {
      s += red1[t * 8 + i];
      s2 += red2[t * 8 + i];
    }
    float mu = s * (1.0f / 768.0f);
    float var = s2 * (1.0f / 768.0f) - mu * mu;
    muA[t] = mu;
    rsA[t] = 1.0f / sqrtf(var + 1e-7f);
  }
  __syncthreads();
#pragma unroll
  for (int nt = 0; nt < 6; ++nt) {
    int gn = w * 96 + nt * 16 + l15;
    float sc = lns[gn], bi = lnb[gn];
#pragma unroll
    for (int mt = 0; mt < 4; ++mt) {
#pragma unroll
      for (int r = 0; r < 4; ++r) {
        int lm = mt * 16 + 4 * g + r;
        float v = (acc[mt][nt][r] - muA[lm]) * rsA[lm] * sc + bi;
        out[(size_t)(m0 + lm) * HID + gn] = v;
      }
    }
  }
}

extern "C" void kernel_launch(void* const* d_in, const int* in_sizes, int n_in,
                              void* d_out, int out_size, void* d_ws,
                              size_t ws_size, hipStream_t stream) {
  (void)in_sizes; (void)n_in; (void)out_size; (void)ws_size;
  const float* hidden = (const float*)d_in[0];
  const float* relpos = (const float*)d_in[1];
  const float* Wq = (const float*)d_in[2];
  const float* bq = (const float*)d_in[3];
  const float* Wk = (const float*)d_in[4];
  const float* bk = (const float*)d_in[5];
  const float* Wv = (const float*)d_in[6];
  const float* bv = (const float*)d_in[7];
  const float* Wo = (const float*)d_in[8];
  const float* bo = (const float*)d_in[9];
  const float* lns = (const float*)d_in[10];
  const float* lnb = (const float*)d_in[11];
  float* out = (float*)d_out;

  // Workspace (ushort units), total 207,618,048 B == proven footprint.
  unsigned short* ws = (unsigned short*)d_ws;
  const size_t QE = (size_t)48 * SEQ * HDIM;   // 25,165,824
  const size_t PE = (size_t)NHEADS * PBUCK * HDIM;  // 393,216
  unsigned short* qws = ws;
  unsigned short* kws = qws + QE;
  unsigned short* vws = kws + QE;
  unsigned short* ctx = vws + QE;
  unsigned short* hbf = ctx;                   // alias: dead before attn writes
  unsigned short* posq = ctx + QE;
  unsigned short* posk = posq + PE;
  unsigned short* Wt4 = posk + PE;             // 4 x 589,824
  unsigned short* WoT = Wt4 + (size_t)3 * HID * HID;

  static bool attrib_set = false;
  if (!attrib_set) {
    hipFuncSetAttribute((const void*)attn_kernel,
                        hipFuncAttributeMaxDynamicSharedMemorySize, SMEM_ATTN);
    hipFuncSetAttribute((const void*)out_ln,
                        hipFuncAttributeMaxDynamicSharedMemorySize, SMEM_OL);
    attrib_set = true;
  }

  hbf_conv<<<12288, 256, 0, stream>>>(hidden, hbf);
  conv_wt<<<dim3(12, 12, 4), 256, 0, stream>>>(Wq, Wk, Wv, Wo, Wt4);
  pos_gemm<<<dim3(8, 24), 256, 0, stream>>>(relpos, Wq, Wk, bq, bk, posq, posk);
  qkv_mfma<<<4608, 256, 0, stream>>>(hbf, Wt4, bq, bk, bv, qws, kws, vws);
  attn_kernel<<<3072, 512, SMEM_ATTN, stream>>>(qws, kws, vws, posq, posk, ctx);
  out_ln<<<512, 512, SMEM_OL, stream>>>(ctx, WoT, bo, hidden, lns, lnb, out);
}